// Round 10
// baseline (6098.090 us; speedup 1.0000x reference)
//
#include <hip/hip_runtime.h>
#include <hip/hip_bf16.h>
#include <hip/hip_cooperative_groups.h>
#include <cstdint>
#include <cstddef>

namespace cg = cooperative_groups;

// Problem dims
#define B_   64
#define S_   512
#define T_   256
#define E_   512
#define H_   512
#define KQ_  256
#define V_   1000

typedef unsigned short bf16_t;
typedef __attribute__((ext_vector_type(8))) short short8;   // 8 bf16 (4 VGPRs) — MFMA A/B frag
typedef __attribute__((ext_vector_type(4))) float floatx4;  // MFMA C/D frag
typedef __attribute__((ext_vector_type(4))) unsigned int uint4v;

// ---------- small helpers ----------
static __device__ __forceinline__ float bflo(unsigned u){ unsigned x = u << 16;        return __builtin_bit_cast(float, x); }
static __device__ __forceinline__ float bfhi(unsigned u){ unsigned x = u & 0xffff0000u; return __builtin_bit_cast(float, x); }
static __device__ __forceinline__ float bf2f(bf16_t h){ unsigned x = ((unsigned)h) << 16; return __builtin_bit_cast(float, x); }
static __device__ __forceinline__ bf16_t f2bf(float f){
    unsigned u = __builtin_bit_cast(unsigned, f);
    unsigned r = u + 0x7fffu + ((u >> 16) & 1u);   // RNE
    return (bf16_t)(r >> 16);
}
static __device__ __forceinline__ float sigm(float x){ return 1.f / (1.f + __expf(-x)); }
static __device__ __forceinline__ float tanh_(float x){
    float ax = fabsf(x); float t = __expf(-2.f * ax);
    float r = (1.f - t) / (1.f + t);
    return copysignf(r, x);
}
static __device__ __forceinline__ short8 ld8(const bf16_t* p){ return *(const short8*)p; }
// Coherence-point VECTOR load: volatile 16B load -> single global_load_dwordx4 with sc0/sc1
// (bypasses stale L1/L2, reads at coherence point) but schedules/pipelines like a normal
// load. (Round-7 postmortem: per-word ATOMIC loads serialized; this pipelines.)
static __device__ __forceinline__ short8 ld8v(const bf16_t* p){
    uint4v r = *(const volatile uint4v*)p;
    return __builtin_bit_cast(short8, r);
}
static __device__ __forceinline__ floatx4 mfma16(short8 a, short8 b, floatx4 c){
    return __builtin_amdgcn_mfma_f32_16x16x32_bf16(a, b, c, 0, 0, 0);
}

// Shared MFMA K-loop: 4 M-tiles (M=64) x 1 N-tile (N=16) per wave.
// A frag: A[m=lane&15][k=quad*8+j]; B frag from W rows (B^T): B[n=lane&15][k].
// D frag: row(m)=quad*4+r, col(n)=lane&15  (m89-verified convention).
static __device__ __forceinline__ void mfma_kloop(const bf16_t* const rA[4], const bf16_t* rB,
                                                  int K, int quad, floatx4 acc[4]){
    for (int ks = 0; ks < K; ks += 32){
        int ko = ks + quad * 8;
        short8 bf = ld8(rB + ko);
        #pragma unroll
        for (int mi = 0; mi < 4; ++mi)
            acc[mi] = mfma16(ld8(rA[mi] + ko), bf, acc[mi]);
    }
}

// ---------- one-time conversion kernel ----------
// Segments (element index): Wcat1 | Wcat2 | emb(pad 1024 rows) | W1 | WqT | Wkv | enc | bcat1 | bcat2 | bkv
#define CV_E0 2097152UL
#define CV_E1 4194304UL
#define CV_E2 4718592UL
#define CV_E3 5242880UL
#define CV_E4 5373952UL
#define CV_E5 5767168UL
#define CV_E6 22544384UL
#define CV_E7 22546432UL
#define CV_E8 22548480UL
#define CV_E9 22549248UL

__global__ __launch_bounds__(256) void convert_kernel(
    const float* __restrict__ enc,  const float* __restrict__ Wemb,
    const float* __restrict__ Wih1, const float* __restrict__ Whh1,
    const float* __restrict__ Wih2, const float* __restrict__ Whh2,
    const float* __restrict__ Wq,   const float* __restrict__ Wk,
    const float* __restrict__ Wv,   const float* __restrict__ W1,
    const float* __restrict__ bih1, const float* __restrict__ bhh1,
    const float* __restrict__ bih2, const float* __restrict__ bhh2,
    const float* __restrict__ bk,   const float* __restrict__ bv,
    bf16_t* __restrict__ Wc1,  bf16_t* __restrict__ Wc2, bf16_t* __restrict__ emb16,
    bf16_t* __restrict__ W116, bf16_t* __restrict__ WqT16, bf16_t* __restrict__ Wkv16,
    bf16_t* __restrict__ enc16, float* __restrict__ bcat1, float* __restrict__ bcat2,
    float* __restrict__ bkvO)
{
    for (size_t i = (size_t)blockIdx.x * 256 + threadIdx.x; i < CV_E9; i += (size_t)gridDim.x * 256){
        if (i < CV_E0){ size_t r = i >> 10, k = i & 1023;
            float v_ = (k < 512) ? Wih1[r*512 + k] : Whh1[r*512 + (k - 512)];
            Wc1[i] = f2bf(v_);
        } else if (i < CV_E1){ size_t l = i - CV_E0, r = l >> 10, k = l & 1023;
            float v_ = (k < 512) ? Wih2[r*512 + k] : Whh2[r*512 + (k - 512)];
            Wc2[l] = f2bf(v_);
        } else if (i < CV_E2){ size_t l = i - CV_E1, r = l >> 9, k = l & 511;
            emb16[l] = f2bf(r < 1000 ? Wemb[r*512 + k] : 0.f);
        } else if (i < CV_E3){ size_t l = i - CV_E2;
            W116[l] = f2bf(W1[l]);
        } else if (i < CV_E4){ size_t l = i - CV_E3, h = l >> 8, nn = l & 255;
            WqT16[l] = f2bf(Wq[nn*512 + h]);     // WqT[h][d] = Wq[d][h]
        } else if (i < CV_E5){ size_t l = i - CV_E4, r = l >> 9, k = l & 511;
            float v_ = (r < 256) ? Wk[r*512 + k] : Wv[(r - 256)*512 + k];
            Wkv16[l] = f2bf(v_);
        } else if (i < CV_E6){ size_t l = i - CV_E5;
            enc16[l] = f2bf(enc[l]);
        } else if (i < CV_E7){ size_t l = i - CV_E6; bcat1[l] = bih1[l] + bhh1[l]; }
        else if (i < CV_E8){ size_t l = i - CV_E7; bcat2[l] = bih2[l] + bhh2[l]; }
        else { size_t l = i - CV_E8; bkvO[l] = (l < 256) ? bk[l] : bv[l - 256]; }
    }
}

// ---------- k/v projection: [k|v](m,n) = enc(m,:) . Wkv(n,:) + bkv(n);  M=32768, N=768, K=512 ----------
__global__ __launch_bounds__(256) void gemm_kv_kernel(
    const bf16_t* __restrict__ enc16, const bf16_t* __restrict__ Wkv16,
    const float* __restrict__ bkv, bf16_t* __restrict__ kq16, bf16_t* __restrict__ vT16)
{
    __shared__ bf16_t tile[64][72];   // 64 m(s) x 64 n(e), pad 72 vs bank conflicts
    const int tid = threadIdx.x, lane = tid & 63, wv = tid >> 6, ml = lane & 15, quad = lane >> 4;
    const int mb = blockIdx.x, nb = blockIdx.y;
    const int n = nb*64 + wv*16 + ml;
    const bf16_t* brow = Wkv16 + (size_t)n * 512;
    const bf16_t* rA[4];
    #pragma unroll
    for (int mi = 0; mi < 4; ++mi) rA[mi] = enc16 + (size_t)(mb*64 + mi*16 + ml) * 512;
    floatx4 acc[4];
    #pragma unroll
    for (int mi = 0; mi < 4; ++mi) acc[mi] = (floatx4){0.f, 0.f, 0.f, 0.f};
    mfma_kloop(rA, brow, 512, quad, acc);
    const float bias = bkv[n];
    if (nb < 4){
        #pragma unroll
        for (int mi = 0; mi < 4; ++mi)
            #pragma unroll
            for (int r = 0; r < 4; ++r){
                int m = mb*64 + mi*16 + quad*4 + r;
                kq16[(size_t)m*256 + n] = f2bf(acc[mi][r] + bias);
            }
    } else {
        #pragma unroll
        for (int mi = 0; mi < 4; ++mi)
            #pragma unroll
            for (int r = 0; r < 4; ++r)
                tile[mi*16 + quad*4 + r][wv*16 + ml] = f2bf(acc[mi][r] + bias);
        __syncthreads();
        const int b = mb >> 3, s0 = (mb & 7) * 64, e0 = nb*64 - 256;
        const int eloc = tid >> 2, sc = (tid & 3) * 16;
        bf16_t* dst = vT16 + ((size_t)(b*512 + e0 + eloc)) * 512 + s0 + sc;
        #pragma unroll
        for (int j = 0; j < 16; ++j) dst[j] = tile[sc + j][eloc];
    }
}

// ---------- k2 = k @ Wq: M=32768, N=512, K=256 ----------
__global__ __launch_bounds__(256) void gemm_k2_kernel(
    const bf16_t* __restrict__ kq16, const bf16_t* __restrict__ WqT16, bf16_t* __restrict__ k216)
{
    const int tid = threadIdx.x, lane = tid & 63, wv = tid >> 6, ml = lane & 15, quad = lane >> 4;
    const int mb = blockIdx.x, nb = blockIdx.y;
    const int n = nb*64 + wv*16 + ml;
    const bf16_t* brow = WqT16 + (size_t)n * 256;
    const bf16_t* rA[4];
    #pragma unroll
    for (int mi = 0; mi < 4; ++mi) rA[mi] = kq16 + (size_t)(mb*64 + mi*16 + ml) * 256;
    floatx4 acc[4];
    #pragma unroll
    for (int mi = 0; mi < 4; ++mi) acc[mi] = (floatx4){0.f, 0.f, 0.f, 0.f};
    mfma_kloop(rA, brow, 256, quad, acc);
    #pragma unroll
    for (int mi = 0; mi < 4; ++mi)
        #pragma unroll
        for (int r = 0; r < 4; ++r){
            int m = mb*64 + mi*16 + quad*4 + r;
            k216[(size_t)m*512 + n] = f2bf(acc[mi][r]);
        }
}

// ---------- kb[m] = k[m,:] . bq ----------
__global__ __launch_bounds__(256) void kbias_kernel(
    const bf16_t* __restrict__ kq16, const float* __restrict__ bq, float* __restrict__ kb)
{
    int m = blockIdx.x * 256 + threadIdx.x;  // 32768 total
    const unsigned* row = (const unsigned*)(kq16 + (size_t)m * 256);
    float acc = 0.f;
    #pragma unroll 8
    for (int i = 0; i < 128; ++i){
        unsigned u = row[i];
        acc += bflo(u) * bq[2*i] + bfhi(u) * bq[2*i + 1];
    }
    kb[m] = acc;
}

// ---------- cooperative scan: ONLY the recurrent LSTM chain ----------
// Period p: LSTM1(t=p) on blocks 0..31 | LSTM2(t=p-1) on blocks 32..63.
// Round-9 postmortem: rounds 6/8/9 (three different data paths) all hit 18.8-19.0 us/period
// with identical FETCH_SIZE -> data path is NOT the bottleneck. The untouched common part
// is the barrier POLL: 64 blocks each gather-poll 64 contended flag lines (~4096
// coherence-point requests per round).
// Round-10: TWO-LEVEL barrier (single-variable A/B vs round 8):
//   arrival: each block fetch_adds its OWN flag (uncontended, proven).
//   detect:  ONLY block 0 polls the 64 flags (sole reader -> no contention), then
//            publishes a single go word = p+1.
//   wait:    blocks 1..63 poll the go word with ONE lane (64 requests/round, not 4096).
// Ordering (all at coherence point): h stores drained by per-wave vmcnt before s_barrier ->
// flag add -> block0 reads flags -> go store (program order after poll loads) ->
// consumers read go -> volatile h loads (cannot hoist past __syncthreads).
#define LG(w_, b_, j_) smemf[((w_)*64 + (b_))*17 + (j_)]

struct ScanParams {
    const int* y;
    const bf16_t *emb16, *Wc1, *Wc2;
    const float *bcat1, *bcat2;
    bf16_t *h1, *h2, *h2all;
    unsigned* bar;    // 64 arrival flags + 1 go word, 32-uint (128B) stride
};

#define SPER (T_ + 1)   // 257 periods
#define NBLK 64
#define FSTRIDE 32      // uints between flags (128B)

__global__ __launch_bounds__(512, 2) void scan_kernel(ScanParams P)
{
    __shared__ __align__(16) float smemf[8704];
    const int bx = blockIdx.x, tid = threadIdx.x;
    const size_t BH = (size_t)B_ * H_;
    const int lane = tid & 63, w = tid >> 6, ml = lane & 15, quad = lane >> 4;
    const int g = w & 3, kh = w >> 2;
    const int isL1 = (bx < 32);
    const int jblk = isL1 ? bx : (bx - 32);
    const int j0 = jblk * 16;
    // wave-uniform: does this wave's A-operand cross blocks (needs coherent loads)?
    const bool coh = (kh == 1) || (!isL1);
    unsigned* const go = &P.bar[(size_t)NBLK * FSTRIDE];

    // ---- loop-invariant state in registers ----
    const bf16_t* Wcat = isL1 ? P.Wc1 : P.Wc2;
    const float*  bct  = isL1 ? P.bcat1 : P.bcat2;
    const bf16_t* browg = Wcat + (size_t)(g*512 + j0 + ml) * 1024 + (size_t)kh * 512;
    short8 wfrag[16];
    #pragma unroll
    for (int i = 0; i < 16; ++i){
        wfrag[i] = ld8(browg + i*32 + quad*8);
        asm volatile("" : "+v"(wfrag[i]));   // opaque: non-rematerializable -> stays in VGPRs
    }

    // cell-phase mapping: thread -> (batch bb, j-PAIR q_) so h writes pack into one u32
    const int q_ = tid & 7, bb = tid >> 3;        // bb in [0,64), q_ in [0,8)
    const int j = j0 + 2*q_;                      // even
    const float bi0 = bct[j],        bi1 = bct[j + 1];
    const float bf0 = bct[512 + j],  bf1 = bct[512 + j + 1];
    const float bg0 = bct[1024 + j], bg1 = bct[1024 + j + 1];
    const float bo0 = bct[1536 + j], bo1 = bct[1536 + j + 1];
    float creg0 = 0.f, creg1 = 0.f;               // c-state for (bb, j) and (bb, j+1)

    for (int p = 0; p < SPER; ++p){
        const int t = isL1 ? p : (p - 1);
        if (t >= 0 && t < T_){
            const bf16_t* h_in  = (isL1 ? P.h1 : P.h2) + (size_t)((t - 1) & 1) * BH;
            bf16_t*       h_out = (isL1 ? P.h1 : P.h2) + (size_t)(t & 1) * BH;
            const bf16_t* x_h1  = P.h1 + (size_t)(t & 1) * BH;   // LSTM2 x-input = h1(t)

            // ---- MFMA phase ----
            const bf16_t* rA[4];
            #pragma unroll
            for (int mi = 0; mi < 4; ++mi){
                int b = mi*16 + ml;
                if (kh == 0){
                    if (isL1){
                        int tok = (t == 0) ? 0 : P.y[b * T_ + (t - 1)];   // SOS=0
                        rA[mi] = P.emb16 + (size_t)tok * 512;
                    } else {
                        rA[mi] = x_h1 + (size_t)b * 512;
                    }
                } else {
                    rA[mi] = h_in + (size_t)b * 512;
                }
            }
            floatx4 acc[4];
            #pragma unroll
            for (int mi = 0; mi < 4; ++mi) acc[mi] = (floatx4){0.f, 0.f, 0.f, 0.f};
            if (coh){
                #pragma unroll
                for (int ks16 = 0; ks16 < 16; ++ks16){
                    int ko = ks16*32 + quad*8;
                    short8 bf = wfrag[ks16];
                    #pragma unroll
                    for (int mi = 0; mi < 4; ++mi)
                        acc[mi] = mfma16(ld8v(rA[mi] + ko), bf, acc[mi]);
                }
            } else {
                #pragma unroll
                for (int ks16 = 0; ks16 < 16; ++ks16){
                    int ko = ks16*32 + quad*8;
                    short8 bf = wfrag[ks16];
                    #pragma unroll
                    for (int mi = 0; mi < 4; ++mi)
                        acc[mi] = mfma16(ld8(rA[mi] + ko), bf, acc[mi]);
                }
            }
            #pragma unroll
            for (int mi = 0; mi < 4; ++mi)
                #pragma unroll
                for (int r = 0; r < 4; ++r)
                    LG(w, mi*16 + quad*4 + r, ml) = acc[mi][r];
            __syncthreads();
            // ---- cell phase: 512 threads x (1 batch, 2 adjacent j) ----
            {
                float gi0 = LG(0, bb, 2*q_)   + LG(4, bb, 2*q_)   + bi0;
                float gf_0= LG(1, bb, 2*q_)   + LG(5, bb, 2*q_)   + bf0;
                float gg0 = LG(2, bb, 2*q_)   + LG(6, bb, 2*q_)   + bg0;
                float go0 = LG(3, bb, 2*q_)   + LG(7, bb, 2*q_)   + bo0;
                float gi1 = LG(0, bb, 2*q_+1) + LG(4, bb, 2*q_+1) + bi1;
                float gf_1= LG(1, bb, 2*q_+1) + LG(5, bb, 2*q_+1) + bf1;
                float gg1 = LG(2, bb, 2*q_+1) + LG(6, bb, 2*q_+1) + bg1;
                float go1 = LG(3, bb, 2*q_+1) + LG(7, bb, 2*q_+1) + bo1;
                float cn0 = sigm(gf_0) * creg0 + sigm(gi0) * tanh_(gg0);
                float cn1 = sigm(gf_1) * creg1 + sigm(gi1) * tanh_(gg1);
                float hn0 = sigm(go0) * tanh_(cn0);
                float hn1 = sigm(go1) * tanh_(cn1);
                creg0 = cn0; creg1 = cn1;
                unsigned pk = (unsigned)f2bf(hn0) | ((unsigned)f2bf(hn1) << 16);
                // write-through to coherence point (round-7/8-proven path)
                __hip_atomic_store((unsigned*)h_out + ((size_t)bb*256 + (j0 >> 1) + q_), pk,
                                   __ATOMIC_RELAXED, __HIP_MEMORY_SCOPE_AGENT);
                if (!isL1)
                    __hip_atomic_store((unsigned*)P.h2all + (((size_t)bb*T_ + t)*256 + (j0 >> 1) + q_), pk,
                                       __ATOMIC_RELAXED, __HIP_MEMORY_SCOPE_AGENT);
            }
        }
        // ---- two-level grid barrier ----
        __syncthreads();   // every wave drains its own vmem (vmcnt(0) before s_barrier)
        if (tid == 0){
            asm volatile("s_waitcnt vmcnt(0)" ::: "memory");   // belt-and-braces drain
            __hip_atomic_fetch_add(&P.bar[(size_t)bx * FSTRIDE], 1u,
                                   __ATOMIC_RELAXED, __HIP_MEMORY_SCOPE_AGENT);
        }
        if (bx == 0 && tid < NBLK){
            // sole reader of the arrival flags -> uncontended poll
            while (__hip_atomic_load(&P.bar[(size_t)tid * FSTRIDE],
                                     __ATOMIC_RELAXED, __HIP_MEMORY_SCOPE_AGENT)
                   < (unsigned)(p + 1))
                __builtin_amdgcn_s_sleep(1);
            if (tid == 0)
                __hip_atomic_store(go, (unsigned)(p + 1),
                                   __ATOMIC_RELAXED, __HIP_MEMORY_SCOPE_AGENT);
        }
        if (bx != 0 && tid == 0){
            // single-lane poll of ONE read-mostly line
            while (__hip_atomic_load(go, __ATOMIC_RELAXED, __HIP_MEMORY_SCOPE_AGENT)
                   < (unsigned)(p + 1))
                __builtin_amdgcn_s_sleep(1);
        }
        __syncthreads();   // compiler memory barrier: next-period loads can't hoist
    }
}

// ---------- batched post-scan stages (fully parallel over all 16384 (b,t) rows) ----------

__global__ __launch_bounds__(256) void scores_kernel(
    const bf16_t* __restrict__ h2all, const bf16_t* __restrict__ k216,
    const float* __restrict__ kb, float* __restrict__ raw)
{
    const int tid = threadIdx.x, lane = tid & 63, wv = tid >> 6, ml = lane & 15, quad = lane >> 4;
    const int nt = blockIdx.x, mt = blockIdx.y, b = blockIdx.z;
    const int n = nt*64 + wv*16 + ml;            // s
    const bf16_t* brow = k216 + ((size_t)b*512 + n) * 512;
    const bf16_t* rA[4];
    #pragma unroll
    for (int mi = 0; mi < 4; ++mi)
        rA[mi] = h2all + ((size_t)b*T_ + mt*64 + mi*16 + ml) * 512;
    floatx4 acc[4];
    #pragma unroll
    for (int mi = 0; mi < 4; ++mi) acc[mi] = (floatx4){0.f, 0.f, 0.f, 0.f};
    mfma_kloop(rA, brow, 512, quad, acc);
    const float kbn = kb[(size_t)b*512 + n];
    #pragma unroll
    for (int mi = 0; mi < 4; ++mi)
        #pragma unroll
        for (int r = 0; r < 4; ++r){
            int m = mt*64 + mi*16 + quad*4 + r;  // t
            raw[((size_t)b*T_ + m)*512 + n] = (acc[mi][r] + kbn) * 0.0625f;
        }
}

__global__ __launch_bounds__(512) void softmax_kernel(
    const float* __restrict__ raw, float* __restrict__ out_attn,
    bf16_t* __restrict__ attnb, bf16_t* __restrict__ attnlo)
{
    __shared__ float red[16];
    const int tid = threadIdx.x;
    const size_t r = blockIdx.x;
    float sc = raw[r*512 + tid];
    float mx = sc;
    #pragma unroll
    for (int o = 32; o > 0; o >>= 1) mx = fmaxf(mx, __shfl_xor(mx, o, 64));
    if ((tid & 63) == 0) red[tid >> 6] = mx;
    __syncthreads();
    float gmax = red[0];
    #pragma unroll
    for (int i = 1; i < 8; ++i) gmax = fmaxf(gmax, red[i]);
    float e = __expf(sc - gmax);
    float sm = e;
    #pragma unroll
    for (int o = 32; o > 0; o >>= 1) sm += __shfl_xor(sm, o, 64);
    if ((tid & 63) == 0) red[8 + (tid >> 6)] = sm;
    __syncthreads();
    float tot = red[8];
    #pragma unroll
    for (int i = 1; i < 8; ++i) tot += red[8 + i];
    float attn = e / tot;
    out_attn[r*512 + tid] = attn;
    bf16_t hi = f2bf(attn);
    attnb [r*512 + tid] = hi;
    attnlo[r*512 + tid] = f2bf(attn - bf2f(hi));
}

__global__ __launch_bounds__(256) void ctx_kernel(
    const bf16_t* __restrict__ attnb, const bf16_t* __restrict__ attnlo,
    const bf16_t* __restrict__ vT16, bf16_t* __restrict__ ctxb)
{
    const int tid = threadIdx.x, lane = tid & 63, wv = tid >> 6, ml = lane & 15, quad = lane >> 4;
    const int nt = blockIdx.x, mt = blockIdx.y, b = blockIdx.z;
    const int n = nt*64 + wv*16 + ml;            // e
    const bf16_t* brow = vT16 + ((size_t)b*512 + n) * 512;
    const bf16_t* rA[4]; const bf16_t* rAlo[4];
    #pragma unroll
    for (int mi = 0; mi < 4; ++mi){
        size_t row = (size_t)b*T_ + mt*64 + mi*16 + ml;
        rA[mi]   = attnb  + row * 512;
        rAlo[mi] = attnlo + row * 512;
    }
    floatx4 acc[4];
    #pragma unroll
    for (int mi = 0; mi < 4; ++mi) acc[mi] = (floatx4){0.f, 0.f, 0.f, 0.f};
    mfma_kloop(rA,   brow, 512, quad, acc);
    mfma_kloop(rAlo, brow, 512, quad, acc);
    #pragma unroll
    for (int mi = 0; mi < 4; ++mi)
        #pragma unroll
        for (int r = 0; r < 4; ++r){
            int m = mt*64 + mi*16 + quad*4 + r;  // t
            ctxb[((size_t)b*T_ + m)*512 + n] = f2bf(acc[mi][r]);
        }
}

__global__ __launch_bounds__(512) void hid_kernel(
    const bf16_t* __restrict__ h2all, const bf16_t* __restrict__ ctxb,
    const bf16_t* __restrict__ W116, const float* __restrict__ b1, bf16_t* __restrict__ hid)
{
    const int tid = threadIdx.x, lane = tid & 63, w = tid >> 6, ml = lane & 15, quad = lane >> 4;
    const int nb = blockIdx.x, mb = blockIdx.y;
    const int n = nb*128 + w*16 + ml;
    const bf16_t* brow = W116 + (size_t)n * 1024;
    const bf16_t* rA[4]; const bf16_t* rC[4];
    #pragma unroll
    for (int mi = 0; mi < 4; ++mi){
        size_t m = (size_t)(mb*64 + mi*16 + ml);
        rA[mi] = h2all + m * 512;
        rC[mi] = ctxb  + m * 512;
    }
    floatx4 acc[4];
    #pragma unroll
    for (int mi = 0; mi < 4; ++mi) acc[mi] = (floatx4){0.f, 0.f, 0.f, 0.f};
    mfma_kloop(rA, brow,       512, quad, acc);
    mfma_kloop(rC, brow + 512, 512, quad, acc);
    const float bias = b1[n];
    #pragma unroll
    for (int mi = 0; mi < 4; ++mi)
        #pragma unroll
        for (int r = 0; r < 4; ++r){
            int m = mb*64 + mi*16 + quad*4 + r;
            hid[(size_t)m*512 + n] = f2bf(fmaxf(acc[mi][r] + bias, 0.f));
        }
}

__global__ __launch_bounds__(512) void logits_kernel(
    const bf16_t* __restrict__ hid, const bf16_t* __restrict__ emb16,
    const float* __restrict__ bcls, float* __restrict__ out_logits)
{
    const int tid = threadIdx.x, lane = tid & 63, w = tid >> 6, ml = lane & 15, quad = lane >> 4;
    const int nb = blockIdx.x, mb = blockIdx.y;
    const int n = nb*128 + w*16 + ml;
    const bf16_t* brow = emb16 + (size_t)n * 512;
    const bf16_t* rA[4];
    #pragma unroll
    for (int mi = 0; mi < 4; ++mi) rA[mi] = hid + (size_t)(mb*64 + mi*16 + ml) * 512;
    floatx4 acc[4];
    #pragma unroll
    for (int mi = 0; mi < 4; ++mi) acc[mi] = (floatx4){0.f, 0.f, 0.f, 0.f};
    mfma_kloop(rA, brow, 512, quad, acc);
    if (n < V_){
        const float bias = bcls[n];
        #pragma unroll
        for (int mi = 0; mi < 4; ++mi)
            #pragma unroll
            for (int r = 0; r < 4; ++r){
                int m = mb*64 + mi*16 + quad*4 + r;
                out_logits[(size_t)m * V_ + n] = acc[mi][r] + bias;
            }
    }
}

// ---------------------------------------------------------------------------
extern "C" void kernel_launch(void* const* d_in, const int* in_sizes, int n_in,
                              void* d_out, int out_size, void* d_ws, size_t ws_size,
                              hipStream_t stream)
{
    const float* enc  = (const float*)d_in[0];
    const int*   y    = (const int*)  d_in[1];
    const float* Wemb = (const float*)d_in[2];
    const float* Wih1 = (const float*)d_in[3];  const float* bih1 = (const float*)d_in[4];
    const float* Whh1 = (const float*)d_in[5];  const float* bhh1 = (const float*)d_in[6];
    const float* Wih2 = (const float*)d_in[7];  const float* bih2 = (const float*)d_in[8];
    const float* Whh2 = (const float*)d_in[9];  const float* bhh2 = (const float*)d_in[10];
    const float* Wq   = (const float*)d_in[11]; const float* bq   = (const float*)d_in[12];
    const float* Wk   = (const float*)d_in[13]; const float* bk   = (const float*)d_in[14];
    const float* Wv   = (const float*)d_in[15]; const float* bv   = (const float*)d_in[16];
    const float* W1   = (const float*)d_in[17]; const float* b1   = (const float*)d_in[18];
    const float* bcls = (const float*)d_in[19];

    float* outF = (float*)d_out;
    float* out_logits = outF;
    float* out_attn   = outF + (size_t)B_ * T_ * V_;

    // workspace carve (256B aligned). Peak ~96 MB via aliasing.
    size_t off = 0;
    char* wsb = (char*)d_ws;
    auto carve = [&](size_t bytes) -> void* {
        void* p = wsb + off;
        off += (bytes + 255) & ~(size_t)255;
        return p;
    };
    bf16_t* enc16 = (bf16_t*)carve((size_t)B_*S_*E_*2);     // Region A
    bf16_t* k216  = enc16;
    bf16_t* attnb = enc16;                                   // 16.8MB
    bf16_t* attnlo= enc16 + (size_t)B_*T_*S_;                // +16.8MB = 33.5MB exact
    bf16_t* kq16  = (bf16_t*)carve((size_t)B_*S_*KQ_*2);    // Region B
    bf16_t* h2all = kq16;                                    // B*T*H*2 = 16.8MB exact
    bf16_t* vT16  = (bf16_t*)carve((size_t)B_*S_*E_*2);     // Region C
    bf16_t* hid   = vT16;                                    // 16.8MB <= 33.5MB
    bf16_t* Wc1   = (bf16_t*)carve((size_t)2048*1024*2);
    bf16_t* Wc2   = (bf16_t*)carve((size_t)2048*1024*2);
    bf16_t* emb16 = (bf16_t*)carve((size_t)1024*512*2);     // padded to 1024 rows
    bf16_t* W116  = (bf16_t*)carve((size_t)512*1024*2);
    bf16_t* WqT16 = (bf16_t*)carve((size_t)512*256*2);
    bf16_t* Wkv16 = (bf16_t*)carve((size_t)768*512*2);
    float*  bcat1 = (float*) carve(2048*4);
    float*  bcat2 = (float*) carve(2048*4);
    float*  bkv   = (float*) carve(768*4);
    float*  kb    = (float*) carve((size_t)B_*S_*4);        // 128 KB
    bf16_t* h1b   = (bf16_t*)carve((size_t)2*B_*H_*2);      // ping-pong
    bf16_t* h2b   = (bf16_t*)carve((size_t)2*B_*H_*2);
    unsigned* bar = (unsigned*)carve((NBLK + 1) * FSTRIDE * 4);  // 64 flags + go word

    float*  raw   = out_logits;                              // [16384][512] f32 scratch in out region
    bf16_t* ctxb  = (bf16_t*)((char*)out_logits + (size_t)B_*T_*S_*4);  // next 16.8MB of out region

    // zero recurrent state + barrier flags (ws is poisoned before every call)
    hipMemsetAsync(h1b, 0, (size_t)2*B_*H_*2, stream);
    hipMemsetAsync(h2b, 0, (size_t)2*B_*H_*2, stream);
    hipMemsetAsync(bar, 0, (NBLK + 1) * FSTRIDE * 4, stream);

    // setup: convert weights/enc, project k/v (v transposed), fold Wq into k2, bq into kb
    convert_kernel<<<8192, 256, 0, stream>>>(enc, Wemb, Wih1, Whh1, Wih2, Whh2, Wq, Wk, Wv, W1,
                                             bih1, bhh1, bih2, bhh2, bk, bv,
                                             Wc1, Wc2, emb16, W116, WqT16, Wkv16, enc16,
                                             bcat1, bcat2, bkv);
    gemm_kv_kernel<<<dim3(512, 12), 256, 0, stream>>>(enc16, Wkv16, bkv, kq16, vT16);
    gemm_k2_kernel<<<dim3(512, 8), 256, 0, stream>>>(kq16, WqT16, k216);
    kbias_kernel<<<128, 256, 0, stream>>>(kq16, bq, kb);

    // sequential part: LSTM chain (64-block cooperative kernel; round-8 data path,
    // two-level barrier: uncontended arrival + block-0 aggregation + go broadcast)
    ScanParams sp;
    sp.y = y; sp.emb16 = emb16; sp.Wc1 = Wc1; sp.Wc2 = Wc2;
    sp.bcat1 = bcat1; sp.bcat2 = bcat2;
    sp.h1 = h1b; sp.h2 = h2b; sp.h2all = h2all;
    sp.bar = bar;
    void* kargs[] = { (void*)&sp };
    hipLaunchCooperativeKernel((const void*)scan_kernel, dim3(64), dim3(512), kargs, 0, stream);

    // batch-parallel tail: scores -> softmax -> ctx -> hid -> logits
    scores_kernel <<<dim3(8, 4, B_), 256, 0, stream>>>(h2all, k216, kb, raw);
    softmax_kernel<<<(size_t)B_*T_, 512, 0, stream>>>(raw, out_attn, attnb, attnlo);
    ctx_kernel    <<<dim3(8, 4, B_), 256, 0, stream>>>(attnb, attnlo, vT16, ctxb);
    hid_kernel    <<<dim3(4, 256), 512, 0, stream>>>(h2all, ctxb, W116, b1, hid);
    logits_kernel <<<dim3(8, 256), 512, 0, stream>>>(hid, emb16, bcls, out_logits);
}

// Round 11
// 5987.839 us; speedup vs baseline: 1.0184x; 1.0184x over previous
//
#include <hip/hip_runtime.h>
#include <hip/hip_bf16.h>
#include <hip/hip_cooperative_groups.h>
#include <cstdint>
#include <cstddef>

namespace cg = cooperative_groups;

// Problem dims
#define B_   64
#define S_   512
#define T_   256
#define E_   512
#define H_   512
#define KQ_  256
#define V_   1000

typedef unsigned short bf16_t;
typedef __attribute__((ext_vector_type(8))) short short8;   // 8 bf16 (4 VGPRs) — MFMA A/B frag
typedef __attribute__((ext_vector_type(4))) float floatx4;  // MFMA C/D frag
typedef __attribute__((ext_vector_type(4))) unsigned int uint4v;

// ---------- small helpers ----------
static __device__ __forceinline__ float bflo(unsigned u){ unsigned x = u << 16;        return __builtin_bit_cast(float, x); }
static __device__ __forceinline__ float bfhi(unsigned u){ unsigned x = u & 0xffff0000u; return __builtin_bit_cast(float, x); }
static __device__ __forceinline__ float bf2f(bf16_t h){ unsigned x = ((unsigned)h) << 16; return __builtin_bit_cast(float, x); }
static __device__ __forceinline__ bf16_t f2bf(float f){
    unsigned u = __builtin_bit_cast(unsigned, f);
    unsigned r = u + 0x7fffu + ((u >> 16) & 1u);   // RNE
    return (bf16_t)(r >> 16);
}
static __device__ __forceinline__ float sigm(float x){ return 1.f / (1.f + __expf(-x)); }
static __device__ __forceinline__ float tanh_(float x){
    float ax = fabsf(x); float t = __expf(-2.f * ax);
    float r = (1.f - t) / (1.f + t);
    return copysignf(r, x);
}
static __device__ __forceinline__ short8 ld8(const bf16_t* p){ return *(const short8*)p; }
// Coherence-point VECTOR load: volatile 16B load -> single global_load_dwordx4 with sc0/sc1
// (bypasses stale L1/L2, reads at coherence point) but schedules/pipelines like a normal load.
static __device__ __forceinline__ short8 ld8v(const bf16_t* p){
    uint4v r = *(const volatile uint4v*)p;
    return __builtin_bit_cast(short8, r);
}
static __device__ __forceinline__ floatx4 mfma16(short8 a, short8 b, floatx4 c){
    return __builtin_amdgcn_mfma_f32_16x16x32_bf16(a, b, c, 0, 0, 0);
}

// Shared MFMA K-loop: 4 M-tiles (M=64) x 1 N-tile (N=16) per wave.
// A frag: A[m=lane&15][k=quad*8+j]; B frag from W rows (B^T): B[n=lane&15][k].
// D frag: row(m)=quad*4+r, col(n)=lane&15  (m89-verified convention).
static __device__ __forceinline__ void mfma_kloop(const bf16_t* const rA[4], const bf16_t* rB,
                                                  int K, int quad, floatx4 acc[4]){
    for (int ks = 0; ks < K; ks += 32){
        int ko = ks + quad * 8;
        short8 bf = ld8(rB + ko);
        #pragma unroll
        for (int mi = 0; mi < 4; ++mi)
            acc[mi] = mfma16(ld8(rA[mi] + ko), bf, acc[mi]);
    }
}

// ---------- one-time conversion kernel ----------
// Segments (element index): Wcat1 | Wcat2 | emb(pad 1024 rows) | W1 | WqT | Wkv | enc | bcat1 | bcat2 | bkv
#define CV_E0 2097152UL
#define CV_E1 4194304UL
#define CV_E2 4718592UL
#define CV_E3 5242880UL
#define CV_E4 5373952UL
#define CV_E5 5767168UL
#define CV_E6 22544384UL
#define CV_E7 22546432UL
#define CV_E8 22548480UL
#define CV_E9 22549248UL

__global__ __launch_bounds__(256) void convert_kernel(
    const float* __restrict__ enc,  const float* __restrict__ Wemb,
    const float* __restrict__ Wih1, const float* __restrict__ Whh1,
    const float* __restrict__ Wih2, const float* __restrict__ Whh2,
    const float* __restrict__ Wq,   const float* __restrict__ Wk,
    const float* __restrict__ Wv,   const float* __restrict__ W1,
    const float* __restrict__ bih1, const float* __restrict__ bhh1,
    const float* __restrict__ bih2, const float* __restrict__ bhh2,
    const float* __restrict__ bk,   const float* __restrict__ bv,
    bf16_t* __restrict__ Wc1,  bf16_t* __restrict__ Wc2, bf16_t* __restrict__ emb16,
    bf16_t* __restrict__ W116, bf16_t* __restrict__ WqT16, bf16_t* __restrict__ Wkv16,
    bf16_t* __restrict__ enc16, float* __restrict__ bcat1, float* __restrict__ bcat2,
    float* __restrict__ bkvO)
{
    for (size_t i = (size_t)blockIdx.x * 256 + threadIdx.x; i < CV_E9; i += (size_t)gridDim.x * 256){
        if (i < CV_E0){ size_t r = i >> 10, k = i & 1023;
            float v_ = (k < 512) ? Wih1[r*512 + k] : Whh1[r*512 + (k - 512)];
            Wc1[i] = f2bf(v_);
        } else if (i < CV_E1){ size_t l = i - CV_E0, r = l >> 10, k = l & 1023;
            float v_ = (k < 512) ? Wih2[r*512 + k] : Whh2[r*512 + (k - 512)];
            Wc2[l] = f2bf(v_);
        } else if (i < CV_E2){ size_t l = i - CV_E1, r = l >> 9, k = l & 511;
            emb16[l] = f2bf(r < 1000 ? Wemb[r*512 + k] : 0.f);
        } else if (i < CV_E3){ size_t l = i - CV_E2;
            W116[l] = f2bf(W1[l]);
        } else if (i < CV_E4){ size_t l = i - CV_E3, h = l >> 8, nn = l & 255;
            WqT16[l] = f2bf(Wq[nn*512 + h]);     // WqT[h][d] = Wq[d][h]
        } else if (i < CV_E5){ size_t l = i - CV_E4, r = l >> 9, k = l & 511;
            float v_ = (r < 256) ? Wk[r*512 + k] : Wv[(r - 256)*512 + k];
            Wkv16[l] = f2bf(v_);
        } else if (i < CV_E6){ size_t l = i - CV_E5;
            enc16[l] = f2bf(enc[l]);
        } else if (i < CV_E7){ size_t l = i - CV_E6; bcat1[l] = bih1[l] + bhh1[l]; }
        else if (i < CV_E8){ size_t l = i - CV_E7; bcat2[l] = bih2[l] + bhh2[l]; }
        else { size_t l = i - CV_E8; bkvO[l] = (l < 256) ? bk[l] : bv[l - 256]; }
    }
}

// ---------- k/v projection: [k|v](m,n) = enc(m,:) . Wkv(n,:) + bkv(n);  M=32768, N=768, K=512 ----------
__global__ __launch_bounds__(256) void gemm_kv_kernel(
    const bf16_t* __restrict__ enc16, const bf16_t* __restrict__ Wkv16,
    const float* __restrict__ bkv, bf16_t* __restrict__ kq16, bf16_t* __restrict__ vT16)
{
    __shared__ bf16_t tile[64][72];   // 64 m(s) x 64 n(e), pad 72 vs bank conflicts
    const int tid = threadIdx.x, lane = tid & 63, wv = tid >> 6, ml = lane & 15, quad = lane >> 4;
    const int mb = blockIdx.x, nb = blockIdx.y;
    const int n = nb*64 + wv*16 + ml;
    const bf16_t* brow = Wkv16 + (size_t)n * 512;
    const bf16_t* rA[4];
    #pragma unroll
    for (int mi = 0; mi < 4; ++mi) rA[mi] = enc16 + (size_t)(mb*64 + mi*16 + ml) * 512;
    floatx4 acc[4];
    #pragma unroll
    for (int mi = 0; mi < 4; ++mi) acc[mi] = (floatx4){0.f, 0.f, 0.f, 0.f};
    mfma_kloop(rA, brow, 512, quad, acc);
    const float bias = bkv[n];
    if (nb < 4){
        #pragma unroll
        for (int mi = 0; mi < 4; ++mi)
            #pragma unroll
            for (int r = 0; r < 4; ++r){
                int m = mb*64 + mi*16 + quad*4 + r;
                kq16[(size_t)m*256 + n] = f2bf(acc[mi][r] + bias);
            }
    } else {
        #pragma unroll
        for (int mi = 0; mi < 4; ++mi)
            #pragma unroll
            for (int r = 0; r < 4; ++r)
                tile[mi*16 + quad*4 + r][wv*16 + ml] = f2bf(acc[mi][r] + bias);
        __syncthreads();
        const int b = mb >> 3, s0 = (mb & 7) * 64, e0 = nb*64 - 256;
        const int eloc = tid >> 2, sc = (tid & 3) * 16;
        bf16_t* dst = vT16 + ((size_t)(b*512 + e0 + eloc)) * 512 + s0 + sc;
        #pragma unroll
        for (int j = 0; j < 16; ++j) dst[j] = tile[sc + j][eloc];
    }
}

// ---------- k2 = k @ Wq: M=32768, N=512, K=256 ----------
__global__ __launch_bounds__(256) void gemm_k2_kernel(
    const bf16_t* __restrict__ kq16, const bf16_t* __restrict__ WqT16, bf16_t* __restrict__ k216)
{
    const int tid = threadIdx.x, lane = tid & 63, wv = tid >> 6, ml = lane & 15, quad = lane >> 4;
    const int mb = blockIdx.x, nb = blockIdx.y;
    const int n = nb*64 + wv*16 + ml;
    const bf16_t* brow = WqT16 + (size_t)n * 256;
    const bf16_t* rA[4];
    #pragma unroll
    for (int mi = 0; mi < 4; ++mi) rA[mi] = kq16 + (size_t)(mb*64 + mi*16 + ml) * 256;
    floatx4 acc[4];
    #pragma unroll
    for (int mi = 0; mi < 4; ++mi) acc[mi] = (floatx4){0.f, 0.f, 0.f, 0.f};
    mfma_kloop(rA, brow, 256, quad, acc);
    #pragma unroll
    for (int mi = 0; mi < 4; ++mi)
        #pragma unroll
        for (int r = 0; r < 4; ++r){
            int m = mb*64 + mi*16 + quad*4 + r;
            k216[(size_t)m*512 + n] = f2bf(acc[mi][r]);
        }
}

// ---------- kb[m] = k[m,:] . bq ----------
__global__ __launch_bounds__(256) void kbias_kernel(
    const bf16_t* __restrict__ kq16, const float* __restrict__ bq, float* __restrict__ kb)
{
    int m = blockIdx.x * 256 + threadIdx.x;  // 32768 total
    const unsigned* row = (const unsigned*)(kq16 + (size_t)m * 256);
    float acc = 0.f;
    #pragma unroll 8
    for (int i = 0; i < 128; ++i){
        unsigned u = row[i];
        acc += bflo(u) * bq[2*i] + bfhi(u) * bq[2*i + 1];
    }
    kb[m] = acc;
}

// ---------- cooperative scan + HEATER ----------
// Round-10 postmortem: 4 different barrier protocols, 3 data paths, fence/no-fence — ALL
// land at ~19 us/period, while the cycle model at 2.4 GHz prices the period at <=3 us.
// Hypothesis: with 64/256 CUs at ~1% ALU activity and s_sleep poll loops, DPM drops the
// gfx clock to its idle floor (~350-500 MHz) -> every cycle-level optimization is
// invisible in wall time. Round-11 single-variable test: grid = 256 blocks; blocks 0..63
// run the BYTE-IDENTICAL round-8 scan; blocks 64..255 are register-only FMA HEATERS
// (no memory traffic, no barrier participation) that keep every XCD's clock pinned until
// a done flag flips. If the theory is right the period collapses ~4x with zero change to
// the scan itself.
#define LG(w_, b_, j_) smemf[((w_)*64 + (b_))*17 + (j_)]

struct ScanParams {
    const int* y;
    const bf16_t *emb16, *Wc1, *Wc2;
    const float *bcat1, *bcat2;
    bf16_t *h1, *h2, *h2all;
    unsigned* bar;    // 64 arrival flags (128B stride) + done word at [64*FSTRIDE]
};

#define SPER (T_ + 1)   // 257 periods
#define NBLK 64
#define GRID_TOTAL 256
#define FSTRIDE 32      // uints between flags (128B)

__global__ __launch_bounds__(512, 1) void scan_kernel(ScanParams P)
{
    __shared__ __align__(16) float smemf[8704];
    __shared__ unsigned hdone;
    const int bx = blockIdx.x, tid = threadIdx.x;
    unsigned* const done = &P.bar[(size_t)NBLK * FSTRIDE];

    if (bx >= NBLK){
        // ---------------- HEATER: register-only FMA spin, exits on done flag ----------------
        if (tid == 0) hdone = 0;
        __syncthreads();
        float a = (float)tid * 1.000001f + 0.5f;
        const float bmul = 1.0000001f, cadd = 0.0000001f;
        unsigned dn = 0;
        while (!dn){
            #pragma unroll 16
            for (int i = 0; i < 4096; ++i) a = __builtin_fmaf(a, bmul, cadd);
            asm volatile("" : "+v"(a));     // keep the chain live
            __syncthreads();
            if (tid == 0)
                hdone = __hip_atomic_load(done, __ATOMIC_RELAXED, __HIP_MEMORY_SCOPE_AGENT);
            __syncthreads();
            dn = hdone;
        }
        return;
    }

    // ---------------- SCAN: byte-identical round-8 structure ----------------
    const size_t BH = (size_t)B_ * H_;
    const int lane = tid & 63, w = tid >> 6, ml = lane & 15, quad = lane >> 4;
    const int g = w & 3, kh = w >> 2;
    const int isL1 = (bx < 32);
    const int jblk = isL1 ? bx : (bx - 32);
    const int j0 = jblk * 16;
    const bool coh = (kh == 1) || (!isL1);

    // ---- loop-invariant state in registers ----
    const bf16_t* Wcat = isL1 ? P.Wc1 : P.Wc2;
    const float*  bct  = isL1 ? P.bcat1 : P.bcat2;
    const bf16_t* browg = Wcat + (size_t)(g*512 + j0 + ml) * 1024 + (size_t)kh * 512;
    short8 wfrag[16];
    #pragma unroll
    for (int i = 0; i < 16; ++i){
        wfrag[i] = ld8(browg + i*32 + quad*8);
        asm volatile("" : "+v"(wfrag[i]));   // opaque: non-rematerializable
    }

    const int q_ = tid & 7, bb = tid >> 3;        // cell mapping: (batch bb, j-pair q_)
    const int j = j0 + 2*q_;
    const float bi0 = bct[j],        bi1 = bct[j + 1];
    const float bf0 = bct[512 + j],  bf1 = bct[512 + j + 1];
    const float bg0 = bct[1024 + j], bg1 = bct[1024 + j + 1];
    const float bo0 = bct[1536 + j], bo1 = bct[1536 + j + 1];
    float creg0 = 0.f, creg1 = 0.f;

    for (int p = 0; p < SPER; ++p){
        const int t = isL1 ? p : (p - 1);
        if (t >= 0 && t < T_){
            const bf16_t* h_in  = (isL1 ? P.h1 : P.h2) + (size_t)((t - 1) & 1) * BH;
            bf16_t*       h_out = (isL1 ? P.h1 : P.h2) + (size_t)(t & 1) * BH;
            const bf16_t* x_h1  = P.h1 + (size_t)(t & 1) * BH;   // LSTM2 x-input = h1(t)

            // ---- MFMA phase ----
            const bf16_t* rA[4];
            #pragma unroll
            for (int mi = 0; mi < 4; ++mi){
                int b = mi*16 + ml;
                if (kh == 0){
                    if (isL1){
                        int tok = (t == 0) ? 0 : P.y[b * T_ + (t - 1)];   // SOS=0
                        rA[mi] = P.emb16 + (size_t)tok * 512;
                    } else {
                        rA[mi] = x_h1 + (size_t)b * 512;
                    }
                } else {
                    rA[mi] = h_in + (size_t)b * 512;
                }
            }
            floatx4 acc[4];
            #pragma unroll
            for (int mi = 0; mi < 4; ++mi) acc[mi] = (floatx4){0.f, 0.f, 0.f, 0.f};
            if (coh){
                #pragma unroll
                for (int ks16 = 0; ks16 < 16; ++ks16){
                    int ko = ks16*32 + quad*8;
                    short8 bf = wfrag[ks16];
                    #pragma unroll
                    for (int mi = 0; mi < 4; ++mi)
                        acc[mi] = mfma16(ld8v(rA[mi] + ko), bf, acc[mi]);
                }
            } else {
                #pragma unroll
                for (int ks16 = 0; ks16 < 16; ++ks16){
                    int ko = ks16*32 + quad*8;
                    short8 bf = wfrag[ks16];
                    #pragma unroll
                    for (int mi = 0; mi < 4; ++mi)
                        acc[mi] = mfma16(ld8(rA[mi] + ko), bf, acc[mi]);
                }
            }
            #pragma unroll
            for (int mi = 0; mi < 4; ++mi)
                #pragma unroll
                for (int r = 0; r < 4; ++r)
                    LG(w, mi*16 + quad*4 + r, ml) = acc[mi][r];
            __syncthreads();
            // ---- cell phase ----
            {
                float gi0 = LG(0, bb, 2*q_)   + LG(4, bb, 2*q_)   + bi0;
                float gf_0= LG(1, bb, 2*q_)   + LG(5, bb, 2*q_)   + bf0;
                float gg0 = LG(2, bb, 2*q_)   + LG(6, bb, 2*q_)   + bg0;
                float go0 = LG(3, bb, 2*q_)   + LG(7, bb, 2*q_)   + bo0;
                float gi1 = LG(0, bb, 2*q_+1) + LG(4, bb, 2*q_+1) + bi1;
                float gf_1= LG(1, bb, 2*q_+1) + LG(5, bb, 2*q_+1) + bf1;
                float gg1 = LG(2, bb, 2*q_+1) + LG(6, bb, 2*q_+1) + bg1;
                float go1 = LG(3, bb, 2*q_+1) + LG(7, bb, 2*q_+1) + bo1;
                float cn0 = sigm(gf_0) * creg0 + sigm(gi0) * tanh_(gg0);
                float cn1 = sigm(gf_1) * creg1 + sigm(gi1) * tanh_(gg1);
                float hn0 = sigm(go0) * tanh_(cn0);
                float hn1 = sigm(go1) * tanh_(cn1);
                creg0 = cn0; creg1 = cn1;
                unsigned pk = (unsigned)f2bf(hn0) | ((unsigned)f2bf(hn1) << 16);
                __hip_atomic_store((unsigned*)h_out + ((size_t)bb*256 + (j0 >> 1) + q_), pk,
                                   __ATOMIC_RELAXED, __HIP_MEMORY_SCOPE_AGENT);
                if (!isL1)
                    __hip_atomic_store((unsigned*)P.h2all + (((size_t)bb*T_ + t)*256 + (j0 >> 1) + q_), pk,
                                       __ATOMIC_RELAXED, __HIP_MEMORY_SCOPE_AGENT);
            }
        }
        // ---- distributed-flag grid barrier (round-8-proven) ----
        __syncthreads();
        if (tid < NBLK){
            if (tid == 0){
                asm volatile("s_waitcnt vmcnt(0)" ::: "memory");
                __hip_atomic_fetch_add(&P.bar[(size_t)bx * FSTRIDE], 1u,
                                       __ATOMIC_RELAXED, __HIP_MEMORY_SCOPE_AGENT);
            }
            while (__hip_atomic_load(&P.bar[(size_t)tid * FSTRIDE],
                                     __ATOMIC_RELAXED, __HIP_MEMORY_SCOPE_AGENT)
                   < (unsigned)(p + 1))
                __builtin_amdgcn_s_sleep(1);
        }
        __syncthreads();
    }
    if (bx == 0 && tid == 0)
        __hip_atomic_store(done, 1u, __ATOMIC_RELAXED, __HIP_MEMORY_SCOPE_AGENT);
}

// ---------- batched post-scan stages (fully parallel over all 16384 (b,t) rows) ----------

__global__ __launch_bounds__(256) void scores_kernel(
    const bf16_t* __restrict__ h2all, const bf16_t* __restrict__ k216,
    const float* __restrict__ kb, float* __restrict__ raw)
{
    const int tid = threadIdx.x, lane = tid & 63, wv = tid >> 6, ml = lane & 15, quad = lane >> 4;
    const int nt = blockIdx.x, mt = blockIdx.y, b = blockIdx.z;
    const int n = nt*64 + wv*16 + ml;            // s
    const bf16_t* brow = k216 + ((size_t)b*512 + n) * 512;
    const bf16_t* rA[4];
    #pragma unroll
    for (int mi = 0; mi < 4; ++mi)
        rA[mi] = h2all + ((size_t)b*T_ + mt*64 + mi*16 + ml) * 512;
    floatx4 acc[4];
    #pragma unroll
    for (int mi = 0; mi < 4; ++mi) acc[mi] = (floatx4){0.f, 0.f, 0.f, 0.f};
    mfma_kloop(rA, brow, 512, quad, acc);
    const float kbn = kb[(size_t)b*512 + n];
    #pragma unroll
    for (int mi = 0; mi < 4; ++mi)
        #pragma unroll
        for (int r = 0; r < 4; ++r){
            int m = mt*64 + mi*16 + quad*4 + r;  // t
            raw[((size_t)b*T_ + m)*512 + n] = (acc[mi][r] + kbn) * 0.0625f;
        }
}

__global__ __launch_bounds__(512) void softmax_kernel(
    const float* __restrict__ raw, float* __restrict__ out_attn,
    bf16_t* __restrict__ attnb, bf16_t* __restrict__ attnlo)
{
    __shared__ float red[16];
    const int tid = threadIdx.x;
    const size_t r = blockIdx.x;
    float sc = raw[r*512 + tid];
    float mx = sc;
    #pragma unroll
    for (int o = 32; o > 0; o >>= 1) mx = fmaxf(mx, __shfl_xor(mx, o, 64));
    if ((tid & 63) == 0) red[tid >> 6] = mx;
    __syncthreads();
    float gmax = red[0];
    #pragma unroll
    for (int i = 1; i < 8; ++i) gmax = fmaxf(gmax, red[i]);
    float e = __expf(sc - gmax);
    float sm = e;
    #pragma unroll
    for (int o = 32; o > 0; o >>= 1) sm += __shfl_xor(sm, o, 64);
    if ((tid & 63) == 0) red[8 + (tid >> 6)] = sm;
    __syncthreads();
    float tot = red[8];
    #pragma unroll
    for (int i = 1; i < 8; ++i) tot += red[8 + i];
    float attn = e / tot;
    out_attn[r*512 + tid] = attn;
    bf16_t hi = f2bf(attn);
    attnb [r*512 + tid] = hi;
    attnlo[r*512 + tid] = f2bf(attn - bf2f(hi));
}

__global__ __launch_bounds__(256) void ctx_kernel(
    const bf16_t* __restrict__ attnb, const bf16_t* __restrict__ attnlo,
    const bf16_t* __restrict__ vT16, bf16_t* __restrict__ ctxb)
{
    const int tid = threadIdx.x, lane = tid & 63, wv = tid >> 6, ml = lane & 15, quad = lane >> 4;
    const int nt = blockIdx.x, mt = blockIdx.y, b = blockIdx.z;
    const int n = nt*64 + wv*16 + ml;            // e
    const bf16_t* brow = vT16 + ((size_t)b*512 + n) * 512;
    const bf16_t* rA[4]; const bf16_t* rAlo[4];
    #pragma unroll
    for (int mi = 0; mi < 4; ++mi){
        size_t row = (size_t)b*T_ + mt*64 + mi*16 + ml;
        rA[mi]   = attnb  + row * 512;
        rAlo[mi] = attnlo + row * 512;
    }
    floatx4 acc[4];
    #pragma unroll
    for (int mi = 0; mi < 4; ++mi) acc[mi] = (floatx4){0.f, 0.f, 0.f, 0.f};
    mfma_kloop(rA,   brow, 512, quad, acc);
    mfma_kloop(rAlo, brow, 512, quad, acc);
    #pragma unroll
    for (int mi = 0; mi < 4; ++mi)
        #pragma unroll
        for (int r = 0; r < 4; ++r){
            int m = mt*64 + mi*16 + quad*4 + r;  // t
            ctxb[((size_t)b*T_ + m)*512 + n] = f2bf(acc[mi][r]);
        }
}

__global__ __launch_bounds__(512) void hid_kernel(
    const bf16_t* __restrict__ h2all, const bf16_t* __restrict__ ctxb,
    const bf16_t* __restrict__ W116, const float* __restrict__ b1, bf16_t* __restrict__ hid)
{
    const int tid = threadIdx.x, lane = tid & 63, w = tid >> 6, ml = lane & 15, quad = lane >> 4;
    const int nb = blockIdx.x, mb = blockIdx.y;
    const int n = nb*128 + w*16 + ml;
    const bf16_t* brow = W116 + (size_t)n * 1024;
    const bf16_t* rA[4]; const bf16_t* rC[4];
    #pragma unroll
    for (int mi = 0; mi < 4; ++mi){
        size_t m = (size_t)(mb*64 + mi*16 + ml);
        rA[mi] = h2all + m * 512;
        rC[mi] = ctxb  + m * 512;
    }
    floatx4 acc[4];
    #pragma unroll
    for (int mi = 0; mi < 4; ++mi) acc[mi] = (floatx4){0.f, 0.f, 0.f, 0.f};
    mfma_kloop(rA, brow,       512, quad, acc);
    mfma_kloop(rC, brow + 512, 512, quad, acc);
    const float bias = b1[n];
    #pragma unroll
    for (int mi = 0; mi < 4; ++mi)
        #pragma unroll
        for (int r = 0; r < 4; ++r){
            int m = mb*64 + mi*16 + quad*4 + r;
            hid[(size_t)m*512 + n] = f2bf(fmaxf(acc[mi][r] + bias, 0.f));
        }
}

__global__ __launch_bounds__(512) void logits_kernel(
    const bf16_t* __restrict__ hid, const bf16_t* __restrict__ emb16,
    const float* __restrict__ bcls, float* __restrict__ out_logits)
{
    const int tid = threadIdx.x, lane = tid & 63, w = tid >> 6, ml = lane & 15, quad = lane >> 4;
    const int nb = blockIdx.x, mb = blockIdx.y;
    const int n = nb*128 + w*16 + ml;
    const bf16_t* brow = emb16 + (size_t)n * 512;
    const bf16_t* rA[4];
    #pragma unroll
    for (int mi = 0; mi < 4; ++mi) rA[mi] = hid + (size_t)(mb*64 + mi*16 + ml) * 512;
    floatx4 acc[4];
    #pragma unroll
    for (int mi = 0; mi < 4; ++mi) acc[mi] = (floatx4){0.f, 0.f, 0.f, 0.f};
    mfma_kloop(rA, brow, 512, quad, acc);
    if (n < V_){
        const float bias = bcls[n];
        #pragma unroll
        for (int mi = 0; mi < 4; ++mi)
            #pragma unroll
            for (int r = 0; r < 4; ++r){
                int m = mb*64 + mi*16 + quad*4 + r;
                out_logits[(size_t)m * V_ + n] = acc[mi][r] + bias;
            }
    }
}

// ---------------------------------------------------------------------------
extern "C" void kernel_launch(void* const* d_in, const int* in_sizes, int n_in,
                              void* d_out, int out_size, void* d_ws, size_t ws_size,
                              hipStream_t stream)
{
    const float* enc  = (const float*)d_in[0];
    const int*   y    = (const int*)  d_in[1];
    const float* Wemb = (const float*)d_in[2];
    const float* Wih1 = (const float*)d_in[3];  const float* bih1 = (const float*)d_in[4];
    const float* Whh1 = (const float*)d_in[5];  const float* bhh1 = (const float*)d_in[6];
    const float* Wih2 = (const float*)d_in[7];  const float* bih2 = (const float*)d_in[8];
    const float* Whh2 = (const float*)d_in[9];  const float* bhh2 = (const float*)d_in[10];
    const float* Wq   = (const float*)d_in[11]; const float* bq   = (const float*)d_in[12];
    const float* Wk   = (const float*)d_in[13]; const float* bk   = (const float*)d_in[14];
    const float* Wv   = (const float*)d_in[15]; const float* bv   = (const float*)d_in[16];
    const float* W1   = (const float*)d_in[17]; const float* b1   = (const float*)d_in[18];
    const float* bcls = (const float*)d_in[19];

    float* outF = (float*)d_out;
    float* out_logits = outF;
    float* out_attn   = outF + (size_t)B_ * T_ * V_;

    // workspace carve (256B aligned). Peak ~96 MB via aliasing.
    size_t off = 0;
    char* wsb = (char*)d_ws;
    auto carve = [&](size_t bytes) -> void* {
        void* p = wsb + off;
        off += (bytes + 255) & ~(size_t)255;
        return p;
    };
    bf16_t* enc16 = (bf16_t*)carve((size_t)B_*S_*E_*2);     // Region A
    bf16_t* k216  = enc16;
    bf16_t* attnb = enc16;                                   // 16.8MB
    bf16_t* attnlo= enc16 + (size_t)B_*T_*S_;                // +16.8MB = 33.5MB exact
    bf16_t* kq16  = (bf16_t*)carve((size_t)B_*S_*KQ_*2);    // Region B
    bf16_t* h2all = kq16;                                    // B*T*H*2 = 16.8MB exact
    bf16_t* vT16  = (bf16_t*)carve((size_t)B_*S_*E_*2);     // Region C
    bf16_t* hid   = vT16;                                    // 16.8MB <= 33.5MB
    bf16_t* Wc1   = (bf16_t*)carve((size_t)2048*1024*2);
    bf16_t* Wc2   = (bf16_t*)carve((size_t)2048*1024*2);
    bf16_t* emb16 = (bf16_t*)carve((size_t)1024*512*2);     // padded to 1024 rows
    bf16_t* W116  = (bf16_t*)carve((size_t)512*1024*2);
    bf16_t* WqT16 = (bf16_t*)carve((size_t)512*256*2);
    bf16_t* Wkv16 = (bf16_t*)carve((size_t)768*512*2);
    float*  bcat1 = (float*) carve(2048*4);
    float*  bcat2 = (float*) carve(2048*4);
    float*  bkv   = (float*) carve(768*4);
    float*  kb    = (float*) carve((size_t)B_*S_*4);        // 128 KB
    bf16_t* h1b   = (bf16_t*)carve((size_t)2*B_*H_*2);      // ping-pong
    bf16_t* h2b   = (bf16_t*)carve((size_t)2*B_*H_*2);
    unsigned* bar = (unsigned*)carve((NBLK + 1) * FSTRIDE * 4);  // 64 flags + done word

    float*  raw   = out_logits;                              // [16384][512] f32 scratch in out region
    bf16_t* ctxb  = (bf16_t*)((char*)out_logits + (size_t)B_*T_*S_*4);  // next 16.8MB of out region

    // zero recurrent state + barrier flags (ws is poisoned before every call)
    hipMemsetAsync(h1b, 0, (size_t)2*B_*H_*2, stream);
    hipMemsetAsync(h2b, 0, (size_t)2*B_*H_*2, stream);
    hipMemsetAsync(bar, 0, (NBLK + 1) * FSTRIDE * 4, stream);

    // setup: convert weights/enc, project k/v (v transposed), fold Wq into k2, bq into kb
    convert_kernel<<<8192, 256, 0, stream>>>(enc, Wemb, Wih1, Whh1, Wih2, Whh2, Wq, Wk, Wv, W1,
                                             bih1, bhh1, bih2, bhh2, bk, bv,
                                             Wc1, Wc2, emb16, W116, WqT16, Wkv16, enc16,
                                             bcat1, bcat2, bkv);
    gemm_kv_kernel<<<dim3(512, 12), 256, 0, stream>>>(enc16, Wkv16, bkv, kq16, vT16);
    gemm_k2_kernel<<<dim3(512, 8), 256, 0, stream>>>(kq16, WqT16, k216);
    kbias_kernel<<<128, 256, 0, stream>>>(kq16, bq, kb);

    // sequential part: LSTM chain (round-8 scan on blocks 0..63) + heater blocks 64..255
    // keeping all XCDs' clocks up (DPM-downclock hypothesis test)
    ScanParams sp;
    sp.y = y; sp.emb16 = emb16; sp.Wc1 = Wc1; sp.Wc2 = Wc2;
    sp.bcat1 = bcat1; sp.bcat2 = bcat2;
    sp.h1 = h1b; sp.h2 = h2b; sp.h2all = h2all;
    sp.bar = bar;
    void* kargs[] = { (void*)&sp };
    hipLaunchCooperativeKernel((const void*)scan_kernel, dim3(GRID_TOTAL), dim3(512),
                               kargs, 0, stream);

    // batch-parallel tail: scores -> softmax -> ctx -> hid -> logits
    scores_kernel <<<dim3(8, 4, B_), 256, 0, stream>>>(h2all, k216, kb, raw);
    softmax_kernel<<<(size_t)B_*T_, 512, 0, stream>>>(raw, out_attn, attnb, attnlo);
    ctx_kernel    <<<dim3(8, 4, B_), 256, 0, stream>>>(attnb, attnlo, vT16, ctxb);
    hid_kernel    <<<dim3(4, 256), 512, 0, stream>>>(h2all, ctxb, W116, b1, hid);
    logits_kernel <<<dim3(8, 256), 512, 0, stream>>>(hid, emb16, bcls, out_logits);
}

// Round 12
// 4394.879 us; speedup vs baseline: 1.3875x; 1.3625x over previous
//
#include <hip/hip_runtime.h>
#include <hip/hip_bf16.h>
#include <hip/hip_cooperative_groups.h>
#include <cstdint>
#include <cstddef>

namespace cg = cooperative_groups;

// Problem dims
#define B_   64
#define S_   512
#define T_   256
#define E_   512
#define H_   512
#define KQ_  256
#define V_   1000

typedef unsigned short bf16_t;
typedef __attribute__((ext_vector_type(8))) short short8;   // 8 bf16 (4 VGPRs) — MFMA A/B frag
typedef __attribute__((ext_vector_type(4))) float floatx4;  // MFMA C/D frag
typedef __attribute__((ext_vector_type(4))) unsigned int uint4v;

// ---------- small helpers ----------
static __device__ __forceinline__ float bflo(unsigned u){ unsigned x = u << 16;        return __builtin_bit_cast(float, x); }
static __device__ __forceinline__ float bfhi(unsigned u){ unsigned x = u & 0xffff0000u; return __builtin_bit_cast(float, x); }
static __device__ __forceinline__ float bf2f(bf16_t h){ unsigned x = ((unsigned)h) << 16; return __builtin_bit_cast(float, x); }
static __device__ __forceinline__ bf16_t f2bf(float f){
    unsigned u = __builtin_bit_cast(unsigned, f);
    unsigned r = u + 0x7fffu + ((u >> 16) & 1u);   // RNE
    return (bf16_t)(r >> 16);
}
static __device__ __forceinline__ float sigm(float x){ return 1.f / (1.f + __expf(-x)); }
static __device__ __forceinline__ float tanh_(float x){
    float ax = fabsf(x); float t = __expf(-2.f * ax);
    float r = (1.f - t) / (1.f + t);
    return copysignf(r, x);
}
static __device__ __forceinline__ short8 ld8(const bf16_t* p){ return *(const short8*)p; }
static __device__ __forceinline__ floatx4 mfma16(short8 a, short8 b, floatx4 c){
    return __builtin_amdgcn_mfma_f32_16x16x32_bf16(a, b, c, 0, 0, 0);
}

// Coherent 128B burst: 8 independent sc0/sc1 dwordx4 loads (full MLP, ONE latency
// exposure), one vmcnt(0) INSIDE the asm, then LDS writes at the call site.
// Rationale (r11 postmortem): with VGPR_Count=64 the in-MFMA-loop coherent loads can
// keep only ~8 dwordx4 in flight -> 8 serialized LLC exposures (~5-8 us/period).
// Staging as a 512-thread burst collapses that to ~1 exposure.
static __device__ __forceinline__ void stage128(const bf16_t* src, bf16_t* dst){
    uint4v t0,t1,t2,t3,t4,t5,t6,t7;
    asm volatile(
        "global_load_dwordx4 %0, %8, off sc0 sc1\n\t"
        "global_load_dwordx4 %1, %8, off offset:16 sc0 sc1\n\t"
        "global_load_dwordx4 %2, %8, off offset:32 sc0 sc1\n\t"
        "global_load_dwordx4 %3, %8, off offset:48 sc0 sc1\n\t"
        "global_load_dwordx4 %4, %8, off offset:64 sc0 sc1\n\t"
        "global_load_dwordx4 %5, %8, off offset:80 sc0 sc1\n\t"
        "global_load_dwordx4 %6, %8, off offset:96 sc0 sc1\n\t"
        "global_load_dwordx4 %7, %8, off offset:112 sc0 sc1\n\t"
        "s_waitcnt vmcnt(0)"
        : "=&v"(t0),"=&v"(t1),"=&v"(t2),"=&v"(t3),
          "=&v"(t4),"=&v"(t5),"=&v"(t6),"=&v"(t7)
        : "v"(src)
        : "memory");
    uint4v* d = (uint4v*)dst;
    d[0]=t0; d[1]=t1; d[2]=t2; d[3]=t3; d[4]=t4; d[5]=t5; d[6]=t6; d[7]=t7;
}

// Shared MFMA K-loop: 4 M-tiles (M=64) x 1 N-tile (N=16) per wave.
// A frag: A[m=lane&15][k=quad*8+j]; B frag from W rows (B^T): B[n=lane&15][k].
// D frag: row(m)=quad*4+r, col(n)=lane&15  (m89-verified convention).
static __device__ __forceinline__ void mfma_kloop(const bf16_t* const rA[4], const bf16_t* rB,
                                                  int K, int quad, floatx4 acc[4]){
    for (int ks = 0; ks < K; ks += 32){
        int ko = ks + quad * 8;
        short8 bf = ld8(rB + ko);
        #pragma unroll
        for (int mi = 0; mi < 4; ++mi)
            acc[mi] = mfma16(ld8(rA[mi] + ko), bf, acc[mi]);
    }
}

// ---------- one-time conversion kernel ----------
// Segments (element index): Wcat1 | Wcat2 | emb(pad 1024 rows) | W1 | WqT | Wkv | enc | bcat1 | bcat2 | bkv
#define CV_E0 2097152UL
#define CV_E1 4194304UL
#define CV_E2 4718592UL
#define CV_E3 5242880UL
#define CV_E4 5373952UL
#define CV_E5 5767168UL
#define CV_E6 22544384UL
#define CV_E7 22546432UL
#define CV_E8 22548480UL
#define CV_E9 22549248UL

__global__ __launch_bounds__(256) void convert_kernel(
    const float* __restrict__ enc,  const float* __restrict__ Wemb,
    const float* __restrict__ Wih1, const float* __restrict__ Whh1,
    const float* __restrict__ Wih2, const float* __restrict__ Whh2,
    const float* __restrict__ Wq,   const float* __restrict__ Wk,
    const float* __restrict__ Wv,   const float* __restrict__ W1,
    const float* __restrict__ bih1, const float* __restrict__ bhh1,
    const float* __restrict__ bih2, const float* __restrict__ bhh2,
    const float* __restrict__ bk,   const float* __restrict__ bv,
    bf16_t* __restrict__ Wc1,  bf16_t* __restrict__ Wc2, bf16_t* __restrict__ emb16,
    bf16_t* __restrict__ W116, bf16_t* __restrict__ WqT16, bf16_t* __restrict__ Wkv16,
    bf16_t* __restrict__ enc16, float* __restrict__ bcat1, float* __restrict__ bcat2,
    float* __restrict__ bkvO)
{
    for (size_t i = (size_t)blockIdx.x * 256 + threadIdx.x; i < CV_E9; i += (size_t)gridDim.x * 256){
        if (i < CV_E0){ size_t r = i >> 10, k = i & 1023;
            float v_ = (k < 512) ? Wih1[r*512 + k] : Whh1[r*512 + (k - 512)];
            Wc1[i] = f2bf(v_);
        } else if (i < CV_E1){ size_t l = i - CV_E0, r = l >> 10, k = l & 1023;
            float v_ = (k < 512) ? Wih2[r*512 + k] : Whh2[r*512 + (k - 512)];
            Wc2[l] = f2bf(v_);
        } else if (i < CV_E2){ size_t l = i - CV_E1, r = l >> 9, k = l & 511;
            emb16[l] = f2bf(r < 1000 ? Wemb[r*512 + k] : 0.f);
        } else if (i < CV_E3){ size_t l = i - CV_E2;
            W116[l] = f2bf(W1[l]);
        } else if (i < CV_E4){ size_t l = i - CV_E3, h = l >> 8, nn = l & 255;
            WqT16[l] = f2bf(Wq[nn*512 + h]);     // WqT[h][d] = Wq[d][h]
        } else if (i < CV_E5){ size_t l = i - CV_E4, r = l >> 9, k = l & 511;
            float v_ = (r < 256) ? Wk[r*512 + k] : Wv[(r - 256)*512 + k];
            Wkv16[l] = f2bf(v_);
        } else if (i < CV_E6){ size_t l = i - CV_E5;
            enc16[l] = f2bf(enc[l]);
        } else if (i < CV_E7){ size_t l = i - CV_E6; bcat1[l] = bih1[l] + bhh1[l]; }
        else if (i < CV_E8){ size_t l = i - CV_E7; bcat2[l] = bih2[l] + bhh2[l]; }
        else { size_t l = i - CV_E8; bkvO[l] = (l < 256) ? bk[l] : bv[l - 256]; }
    }
}

// ---------- k/v projection: [k|v](m,n) = enc(m,:) . Wkv(n,:) + bkv(n);  M=32768, N=768, K=512 ----------
__global__ __launch_bounds__(256) void gemm_kv_kernel(
    const bf16_t* __restrict__ enc16, const bf16_t* __restrict__ Wkv16,
    const float* __restrict__ bkv, bf16_t* __restrict__ kq16, bf16_t* __restrict__ vT16)
{
    __shared__ bf16_t tile[64][72];   // 64 m(s) x 64 n(e), pad 72 vs bank conflicts
    const int tid = threadIdx.x, lane = tid & 63, wv = tid >> 6, ml = lane & 15, quad = lane >> 4;
    const int mb = blockIdx.x, nb = blockIdx.y;
    const int n = nb*64 + wv*16 + ml;
    const bf16_t* brow = Wkv16 + (size_t)n * 512;
    const bf16_t* rA[4];
    #pragma unroll
    for (int mi = 0; mi < 4; ++mi) rA[mi] = enc16 + (size_t)(mb*64 + mi*16 + ml) * 512;
    floatx4 acc[4];
    #pragma unroll
    for (int mi = 0; mi < 4; ++mi) acc[mi] = (floatx4){0.f, 0.f, 0.f, 0.f};
    mfma_kloop(rA, brow, 512, quad, acc);
    const float bias = bkv[n];
    if (nb < 4){
        #pragma unroll
        for (int mi = 0; mi < 4; ++mi)
            #pragma unroll
            for (int r = 0; r < 4; ++r){
                int m = mb*64 + mi*16 + quad*4 + r;
                kq16[(size_t)m*256 + n] = f2bf(acc[mi][r] + bias);
            }
    } else {
        #pragma unroll
        for (int mi = 0; mi < 4; ++mi)
            #pragma unroll
            for (int r = 0; r < 4; ++r)
                tile[mi*16 + quad*4 + r][wv*16 + ml] = f2bf(acc[mi][r] + bias);
        __syncthreads();
        const int b = mb >> 3, s0 = (mb & 7) * 64, e0 = nb*64 - 256;
        const int eloc = tid >> 2, sc = (tid & 3) * 16;
        bf16_t* dst = vT16 + ((size_t)(b*512 + e0 + eloc)) * 512 + s0 + sc;
        #pragma unroll
        for (int j = 0; j < 16; ++j) dst[j] = tile[sc + j][eloc];
    }
}

// ---------- k2 = k @ Wq: M=32768, N=512, K=256 ----------
__global__ __launch_bounds__(256) void gemm_k2_kernel(
    const bf16_t* __restrict__ kq16, const bf16_t* __restrict__ WqT16, bf16_t* __restrict__ k216)
{
    const int tid = threadIdx.x, lane = tid & 63, wv = tid >> 6, ml = lane & 15, quad = lane >> 4;
    const int mb = blockIdx.x, nb = blockIdx.y;
    const int n = nb*64 + wv*16 + ml;
    const bf16_t* brow = WqT16 + (size_t)n * 256;
    const bf16_t* rA[4];
    #pragma unroll
    for (int mi = 0; mi < 4; ++mi) rA[mi] = kq16 + (size_t)(mb*64 + mi*16 + ml) * 256;
    floatx4 acc[4];
    #pragma unroll
    for (int mi = 0; mi < 4; ++mi) acc[mi] = (floatx4){0.f, 0.f, 0.f, 0.f};
    mfma_kloop(rA, brow, 256, quad, acc);
    #pragma unroll
    for (int mi = 0; mi < 4; ++mi)
        #pragma unroll
        for (int r = 0; r < 4; ++r){
            int m = mb*64 + mi*16 + quad*4 + r;
            k216[(size_t)m*512 + n] = f2bf(acc[mi][r]);
        }
}

// ---------- kb[m] = k[m,:] . bq ----------
__global__ __launch_bounds__(256) void kbias_kernel(
    const bf16_t* __restrict__ kq16, const float* __restrict__ bq, float* __restrict__ kb)
{
    int m = blockIdx.x * 256 + threadIdx.x;  // 32768 total
    const unsigned* row = (const unsigned*)(kq16 + (size_t)m * 256);
    float acc = 0.f;
    #pragma unroll 8
    for (int i = 0; i < 128; ++i){
        unsigned u = row[i];
        acc += bflo(u) * bq[2*i] + bfhi(u) * bq[2*i + 1];
    }
    kb[m] = acc;
}

// ---------- cooperative scan: ONLY the recurrent LSTM chain ----------
// Period p: LSTM1(t=p) on blocks 0..31 | LSTM2(t=p-1) on blocks 32..63.
// Round-12 = round 9 WITHOUT the LDS-atomic confound:
//   - h staged to LDS with one 512-thread coherent burst (stage128) per matrix.
//   - gate reduction TWO-PHASE, non-atomic: kh=0 waves WRITE gatef[4][64][17],
//     __syncthreads, kh=1 waves ADD (each slot owned by exactly one wave per phase;
//     no atomics -> r9's 1.15e8 bank conflicts should drop back to ~1e7).
//   - no zeroing needed (phase 1 writes).
//   - barrier: round-8-proven distributed flags.
#define LP 520           // LDS row pitch (elems): 1040B, 16B-aligned rows, 2-way bank alias (free)

struct ScanParams {
    const int* y;
    const bf16_t *emb16, *Wc1, *Wc2;
    const float *bcat1, *bcat2;
    bf16_t *h1, *h2, *h2all;
    unsigned* bar;    // 64 flags, 32-uint (128B) stride
};

#define SPER (T_ + 1)   // 257 periods
#define NBLK 64
#define FSTRIDE 32      // uints between flags (128B)

__global__ __launch_bounds__(512, 1) void scan_kernel(ScanParams P)
{
    __shared__ __align__(16) bf16_t hstA[64 * LP];       // 66.6 KB: LSTM2 x-input h1(t)
    __shared__ __align__(16) bf16_t hstB[64 * LP];       // 66.6 KB: recurrent h_in
    __shared__ __align__(16) float  gatef[4 * 64 * 17];  // 17.4 KB gate sums (two-phase)
    const int bx = blockIdx.x, tid = threadIdx.x;
    const size_t BH = (size_t)B_ * H_;
    const int lane = tid & 63, w = tid >> 6, ml = lane & 15, quad = lane >> 4;
    const int g = w & 3, kh = w >> 2;
    const int isL1 = (bx < 32);
    const int jblk = isL1 ? bx : (bx - 32);
    const int j0 = jblk * 16;

    // ---- loop-invariant state in registers ----
    const bf16_t* Wcat = isL1 ? P.Wc1 : P.Wc2;
    const float*  bct  = isL1 ? P.bcat1 : P.bcat2;
    const bf16_t* browg = Wcat + (size_t)(g*512 + j0 + ml) * 1024 + (size_t)kh * 512;
    short8 wfrag[16];
    #pragma unroll
    for (int i = 0; i < 16; ++i){
        wfrag[i] = ld8(browg + i*32 + quad*8);
        asm volatile("" : "+v"(wfrag[i]));   // opaque: non-rematerializable
    }

    // stage mapping: thread -> 128B chunk of a 64x512 bf16 h-matrix
    const int srow = tid >> 3, schk = tid & 7;
    const int soff = srow*512 + schk*64;        // global element offset
    const int doff = srow*LP  + schk*64;        // lds element offset

    // cell-phase mapping: thread -> (batch bb, j-PAIR q_)
    const int q_ = tid & 7, bb = tid >> 3;
    const int j = j0 + 2*q_;
    const float bi0 = bct[j],        bi1 = bct[j + 1];
    const float bf0 = bct[512 + j],  bf1 = bct[512 + j + 1];
    const float bg0 = bct[1024 + j], bg1 = bct[1024 + j + 1];
    const float bo0 = bct[1536 + j], bo1 = bct[1536 + j + 1];
    float creg0 = 0.f, creg1 = 0.f;             // register-resident c-state

    // A-source base for h-fed waves (wave-constant)
    const bf16_t* lbase = (!isL1 && kh == 0) ? hstA : hstB;

    for (int p = 0; p < SPER; ++p){
        const int t = isL1 ? p : (p - 1);
        if (t >= 0 && t < T_){
            // ---- stage h matrices into LDS (one parallel coherent burst each) ----
            if (isL1){
                stage128(P.h1 + (size_t)((t - 1) & 1) * BH + soff, &hstB[doff]);
            } else {
                stage128(P.h1 + (size_t)(t & 1) * BH + soff,       &hstA[doff]);
                stage128(P.h2 + (size_t)((t - 1) & 1) * BH + soff, &hstB[doff]);
            }
            __syncthreads();

            // ---- MFMA phase ----
            floatx4 acc[4];
            #pragma unroll
            for (int mi = 0; mi < 4; ++mi) acc[mi] = (floatx4){0.f, 0.f, 0.f, 0.f};
            if (isL1 && kh == 0){
                // emb-gathered A (block-local, normal cached loads)
                const bf16_t* gA[4];
                #pragma unroll
                for (int mi = 0; mi < 4; ++mi){
                    int b = mi*16 + ml;
                    int tok = (t == 0) ? 0 : P.y[b * T_ + (t - 1)];   // SOS=0
                    gA[mi] = P.emb16 + (size_t)tok * 512;
                }
                #pragma unroll
                for (int ks16 = 0; ks16 < 16; ++ks16){
                    int ko = ks16*32 + quad*8;
                    short8 bf = wfrag[ks16];
                    #pragma unroll
                    for (int mi = 0; mi < 4; ++mi)
                        acc[mi] = mfma16(ld8(gA[mi] + ko), bf, acc[mi]);
                }
            } else {
                // h A-operand from LDS (ds_read_b128)
                const bf16_t* lA[4];
                #pragma unroll
                for (int mi = 0; mi < 4; ++mi) lA[mi] = lbase + (mi*16 + ml) * LP;
                #pragma unroll
                for (int ks16 = 0; ks16 < 16; ++ks16){
                    int ko = ks16*32 + quad*8;
                    short8 bf = wfrag[ks16];
                    #pragma unroll
                    for (int mi = 0; mi < 4; ++mi)
                        acc[mi] = mfma16(ld8(lA[mi] + ko), bf, acc[mi]);
                }
            }
            // ---- two-phase gate reduction (non-atomic; each slot has ONE owner per phase) ----
            if (kh == 0){
                #pragma unroll
                for (int mi = 0; mi < 4; ++mi)
                    #pragma unroll
                    for (int r = 0; r < 4; ++r){
                        int b = mi*16 + quad*4 + r;
                        gatef[(g*64 + b)*17 + ml] = acc[mi][r];
                    }
            }
            __syncthreads();
            if (kh == 1){
                #pragma unroll
                for (int mi = 0; mi < 4; ++mi)
                    #pragma unroll
                    for (int r = 0; r < 4; ++r){
                        int b = mi*16 + quad*4 + r;
                        gatef[(g*64 + b)*17 + ml] += acc[mi][r];
                    }
            }
            __syncthreads();

            // ---- cell phase: 512 threads x (1 batch, 2 adjacent j) ----
            {
                bf16_t* h_out = (isL1 ? P.h1 : P.h2) + (size_t)(t & 1) * BH;
                float gi0 = gatef[(0*64 + bb)*17 + 2*q_]     + bi0;
                float gf_0= gatef[(1*64 + bb)*17 + 2*q_]     + bf0;
                float gg0 = gatef[(2*64 + bb)*17 + 2*q_]     + bg0;
                float go0 = gatef[(3*64 + bb)*17 + 2*q_]     + bo0;
                float gi1 = gatef[(0*64 + bb)*17 + 2*q_ + 1] + bi1;
                float gf_1= gatef[(1*64 + bb)*17 + 2*q_ + 1] + bf1;
                float gg1 = gatef[(2*64 + bb)*17 + 2*q_ + 1] + bg1;
                float go1 = gatef[(3*64 + bb)*17 + 2*q_ + 1] + bo1;
                float cn0 = sigm(gf_0) * creg0 + sigm(gi0) * tanh_(gg0);
                float cn1 = sigm(gf_1) * creg1 + sigm(gi1) * tanh_(gg1);
                float hn0 = sigm(go0) * tanh_(cn0);
                float hn1 = sigm(go1) * tanh_(cn1);
                creg0 = cn0; creg1 = cn1;
                unsigned pk = (unsigned)f2bf(hn0) | ((unsigned)f2bf(hn1) << 16);
                // write-through to coherence point (round-7/8-proven path)
                __hip_atomic_store((unsigned*)h_out + ((size_t)bb*256 + (j0 >> 1) + q_), pk,
                                   __ATOMIC_RELAXED, __HIP_MEMORY_SCOPE_AGENT);
                if (!isL1)
                    __hip_atomic_store((unsigned*)P.h2all + (((size_t)bb*T_ + t)*256 + (j0 >> 1) + q_), pk,
                                       __ATOMIC_RELAXED, __HIP_MEMORY_SCOPE_AGENT);
            }
        }
        // ---- distributed-flag grid barrier (round-8-proven) ----
        __syncthreads();
        if (tid < NBLK){
            if (tid == 0){
                asm volatile("s_waitcnt vmcnt(0)" ::: "memory");   // h stores done at LLC
                __hip_atomic_fetch_add(&P.bar[(size_t)bx * FSTRIDE], 1u,
                                       __ATOMIC_RELAXED, __HIP_MEMORY_SCOPE_AGENT);
            }
            while (__hip_atomic_load(&P.bar[(size_t)tid * FSTRIDE],
                                     __ATOMIC_RELAXED, __HIP_MEMORY_SCOPE_AGENT)
                   < (unsigned)(p + 1))
                __builtin_amdgcn_s_sleep(1);
        }
        __syncthreads();
    }
}

// ---------- batched post-scan stages (fully parallel over all 16384 (b,t) rows) ----------

__global__ __launch_bounds__(256) void scores_kernel(
    const bf16_t* __restrict__ h2all, const bf16_t* __restrict__ k216,
    const float* __restrict__ kb, float* __restrict__ raw)
{
    const int tid = threadIdx.x, lane = tid & 63, wv = tid >> 6, ml = lane & 15, quad = lane >> 4;
    const int nt = blockIdx.x, mt = blockIdx.y, b = blockIdx.z;
    const int n = nt*64 + wv*16 + ml;            // s
    const bf16_t* brow = k216 + ((size_t)b*512 + n) * 512;
    const bf16_t* rA[4];
    #pragma unroll
    for (int mi = 0; mi < 4; ++mi)
        rA[mi] = h2all + ((size_t)b*T_ + mt*64 + mi*16 + ml) * 512;
    floatx4 acc[4];
    #pragma unroll
    for (int mi = 0; mi < 4; ++mi) acc[mi] = (floatx4){0.f, 0.f, 0.f, 0.f};
    mfma_kloop(rA, brow, 512, quad, acc);
    const float kbn = kb[(size_t)b*512 + n];
    #pragma unroll
    for (int mi = 0; mi < 4; ++mi)
        #pragma unroll
        for (int r = 0; r < 4; ++r){
            int m = mt*64 + mi*16 + quad*4 + r;  // t
            raw[((size_t)b*T_ + m)*512 + n] = (acc[mi][r] + kbn) * 0.0625f;
        }
}

__global__ __launch_bounds__(512) void softmax_kernel(
    const float* __restrict__ raw, float* __restrict__ out_attn,
    bf16_t* __restrict__ attnb, bf16_t* __restrict__ attnlo)
{
    __shared__ float red[16];
    const int tid = threadIdx.x;
    const size_t r = blockIdx.x;
    float sc = raw[r*512 + tid];
    float mx = sc;
    #pragma unroll
    for (int o = 32; o > 0; o >>= 1) mx = fmaxf(mx, __shfl_xor(mx, o, 64));
    if ((tid & 63) == 0) red[tid >> 6] = mx;
    __syncthreads();
    float gmax = red[0];
    #pragma unroll
    for (int i = 1; i < 8; ++i) gmax = fmaxf(gmax, red[i]);
    float e = __expf(sc - gmax);
    float sm = e;
    #pragma unroll
    for (int o = 32; o > 0; o >>= 1) sm += __shfl_xor(sm, o, 64);
    if ((tid & 63) == 0) red[8 + (tid >> 6)] = sm;
    __syncthreads();
    float tot = red[8];
    #pragma unroll
    for (int i = 1; i < 8; ++i) tot += red[8 + i];
    float attn = e / tot;
    out_attn[r*512 + tid] = attn;
    bf16_t hi = f2bf(attn);
    attnb [r*512 + tid] = hi;
    attnlo[r*512 + tid] = f2bf(attn - bf2f(hi));
}

__global__ __launch_bounds__(256) void ctx_kernel(
    const bf16_t* __restrict__ attnb, const bf16_t* __restrict__ attnlo,
    const bf16_t* __restrict__ vT16, bf16_t* __restrict__ ctxb)
{
    const int tid = threadIdx.x, lane = tid & 63, wv = tid >> 6, ml = lane & 15, quad = lane >> 4;
    const int nt = blockIdx.x, mt = blockIdx.y, b = blockIdx.z;
    const int n = nt*64 + wv*16 + ml;            // e
    const bf16_t* brow = vT16 + ((size_t)b*512 + n) * 512;
    const bf16_t* rA[4]; const bf16_t* rAlo[4];
    #pragma unroll
    for (int mi = 0; mi < 4; ++mi){
        size_t row = (size_t)b*T_ + mt*64 + mi*16 + ml;
        rA[mi]   = attnb  + row * 512;
        rAlo[mi] = attnlo + row * 512;
    }
    floatx4 acc[4];
    #pragma unroll
    for (int mi = 0; mi < 4; ++mi) acc[mi] = (floatx4){0.f, 0.f, 0.f, 0.f};
    mfma_kloop(rA,   brow, 512, quad, acc);
    mfma_kloop(rAlo, brow, 512, quad, acc);
    #pragma unroll
    for (int mi = 0; mi < 4; ++mi)
        #pragma unroll
        for (int r = 0; r < 4; ++r){
            int m = mt*64 + mi*16 + quad*4 + r;  // t
            ctxb[((size_t)b*T_ + m)*512 + n] = f2bf(acc[mi][r]);
        }
}

__global__ __launch_bounds__(512) void hid_kernel(
    const bf16_t* __restrict__ h2all, const bf16_t* __restrict__ ctxb,
    const bf16_t* __restrict__ W116, const float* __restrict__ b1, bf16_t* __restrict__ hid)
{
    const int tid = threadIdx.x, lane = tid & 63, w = tid >> 6, ml = lane & 15, quad = lane >> 4;
    const int nb = blockIdx.x, mb = blockIdx.y;
    const int n = nb*128 + w*16 + ml;
    const bf16_t* brow = W116 + (size_t)n * 1024;
    const bf16_t* rA[4]; const bf16_t* rC[4];
    #pragma unroll
    for (int mi = 0; mi < 4; ++mi){
        size_t m = (size_t)(mb*64 + mi*16 + ml);
        rA[mi] = h2all + m * 512;
        rC[mi] = ctxb  + m * 512;
    }
    floatx4 acc[4];
    #pragma unroll
    for (int mi = 0; mi < 4; ++mi) acc[mi] = (floatx4){0.f, 0.f, 0.f, 0.f};
    mfma_kloop(rA, brow,       512, quad, acc);
    mfma_kloop(rC, brow + 512, 512, quad, acc);
    const float bias = b1[n];
    #pragma unroll
    for (int mi = 0; mi < 4; ++mi)
        #pragma unroll
        for (int r = 0; r < 4; ++r){
            int m = mb*64 + mi*16 + quad*4 + r;
            hid[(size_t)m*512 + n] = f2bf(fmaxf(acc[mi][r] + bias, 0.f));
        }
}

__global__ __launch_bounds__(512) void logits_kernel(
    const bf16_t* __restrict__ hid, const bf16_t* __restrict__ emb16,
    const float* __restrict__ bcls, float* __restrict__ out_logits)
{
    const int tid = threadIdx.x, lane = tid & 63, w = tid >> 6, ml = lane & 15, quad = lane >> 4;
    const int nb = blockIdx.x, mb = blockIdx.y;
    const int n = nb*128 + w*16 + ml;
    const bf16_t* brow = emb16 + (size_t)n * 512;
    const bf16_t* rA[4];
    #pragma unroll
    for (int mi = 0; mi < 4; ++mi) rA[mi] = hid + (size_t)(mb*64 + mi*16 + ml) * 512;
    floatx4 acc[4];
    #pragma unroll
    for (int mi = 0; mi < 4; ++mi) acc[mi] = (floatx4){0.f, 0.f, 0.f, 0.f};
    mfma_kloop(rA, brow, 512, quad, acc);
    if (n < V_){
        const float bias = bcls[n];
        #pragma unroll
        for (int mi = 0; mi < 4; ++mi)
            #pragma unroll
            for (int r = 0; r < 4; ++r){
                int m = mb*64 + mi*16 + quad*4 + r;
                out_logits[(size_t)m * V_ + n] = acc[mi][r] + bias;
            }
    }
}

// ---------------------------------------------------------------------------
extern "C" void kernel_launch(void* const* d_in, const int* in_sizes, int n_in,
                              void* d_out, int out_size, void* d_ws, size_t ws_size,
                              hipStream_t stream)
{
    const float* enc  = (const float*)d_in[0];
    const int*   y    = (const int*)  d_in[1];
    const float* Wemb = (const float*)d_in[2];
    const float* Wih1 = (const float*)d_in[3];  const float* bih1 = (const float*)d_in[4];
    const float* Whh1 = (const float*)d_in[5];  const float* bhh1 = (const float*)d_in[6];
    const float* Wih2 = (const float*)d_in[7];  const float* bih2 = (const float*)d_in[8];
    const float* Whh2 = (const float*)d_in[9];  const float* bhh2 = (const float*)d_in[10];
    const float* Wq   = (const float*)d_in[11]; const float* bq   = (const float*)d_in[12];
    const float* Wk   = (const float*)d_in[13]; const float* bk   = (const float*)d_in[14];
    const float* Wv   = (const float*)d_in[15]; const float* bv   = (const float*)d_in[16];
    const float* W1   = (const float*)d_in[17]; const float* b1   = (const float*)d_in[18];
    const float* bcls = (const float*)d_in[19];

    float* outF = (float*)d_out;
    float* out_logits = outF;
    float* out_attn   = outF + (size_t)B_ * T_ * V_;

    // workspace carve (256B aligned). Peak ~96 MB via aliasing.
    size_t off = 0;
    char* wsb = (char*)d_ws;
    auto carve = [&](size_t bytes) -> void* {
        void* p = wsb + off;
        off += (bytes + 255) & ~(size_t)255;
        return p;
    };
    bf16_t* enc16 = (bf16_t*)carve((size_t)B_*S_*E_*2);     // Region A
    bf16_t* k216  = enc16;
    bf16_t* attnb = enc16;                                   // 16.8MB
    bf16_t* attnlo= enc16 + (size_t)B_*T_*S_;                // +16.8MB = 33.5MB exact
    bf16_t* kq16  = (bf16_t*)carve((size_t)B_*S_*KQ_*2);    // Region B
    bf16_t* h2all = kq16;                                    // B*T*H*2 = 16.8MB exact
    bf16_t* vT16  = (bf16_t*)carve((size_t)B_*S_*E_*2);     // Region C
    bf16_t* hid   = vT16;                                    // 16.8MB <= 33.5MB
    bf16_t* Wc1   = (bf16_t*)carve((size_t)2048*1024*2);
    bf16_t* Wc2   = (bf16_t*)carve((size_t)2048*1024*2);
    bf16_t* emb16 = (bf16_t*)carve((size_t)1024*512*2);     // padded to 1024 rows
    bf16_t* W116  = (bf16_t*)carve((size_t)512*1024*2);
    bf16_t* WqT16 = (bf16_t*)carve((size_t)512*256*2);
    bf16_t* Wkv16 = (bf16_t*)carve((size_t)768*512*2);
    float*  bcat1 = (float*) carve(2048*4);
    float*  bcat2 = (float*) carve(2048*4);
    float*  bkv   = (float*) carve(768*4);
    float*  kb    = (float*) carve((size_t)B_*S_*4);        // 128 KB
    bf16_t* h1b   = (bf16_t*)carve((size_t)2*B_*H_*2);      // ping-pong
    bf16_t* h2b   = (bf16_t*)carve((size_t)2*B_*H_*2);
    unsigned* bar = (unsigned*)carve(NBLK * FSTRIDE * 4);    // 64 distributed flags, 128B apart

    float*  raw   = out_logits;                              // [16384][512] f32 scratch in out region
    bf16_t* ctxb  = (bf16_t*)((char*)out_logits + (size_t)B_*T_*S_*4);  // next 16.8MB of out region

    // zero recurrent state + barrier flags (ws is poisoned before every call)
    hipMemsetAsync(h1b, 0, (size_t)2*B_*H_*2, stream);
    hipMemsetAsync(h2b, 0, (size_t)2*B_*H_*2, stream);
    hipMemsetAsync(bar, 0, NBLK * FSTRIDE * 4, stream);

    // setup: convert weights/enc, project k/v (v transposed), fold Wq into k2, bq into kb
    convert_kernel<<<8192, 256, 0, stream>>>(enc, Wemb, Wih1, Whh1, Wih2, Whh2, Wq, Wk, Wv, W1,
                                             bih1, bhh1, bih2, bhh2, bk, bv,
                                             Wc1, Wc2, emb16, W116, WqT16, Wkv16, enc16,
                                             bcat1, bcat2, bkv);
    gemm_kv_kernel<<<dim3(512, 12), 256, 0, stream>>>(enc16, Wkv16, bkv, kq16, vT16);
    gemm_k2_kernel<<<dim3(512, 8), 256, 0, stream>>>(kq16, WqT16, k216);
    kbias_kernel<<<128, 256, 0, stream>>>(kq16, bq, kb);

    // sequential part: LSTM chain (64-block cooperative kernel; LDS-staged h exchange,
    // two-phase non-atomic gate reduction, register weights/c-state, distributed barrier)
    ScanParams sp;
    sp.y = y; sp.emb16 = emb16; sp.Wc1 = Wc1; sp.Wc2 = Wc2;
    sp.bcat1 = bcat1; sp.bcat2 = bcat2;
    sp.h1 = h1b; sp.h2 = h2b; sp.h2all = h2all;
    sp.bar = bar;
    void* kargs[] = { (void*)&sp };
    hipLaunchCooperativeKernel((const void*)scan_kernel, dim3(64), dim3(512), kargs, 0, stream);

    // batch-parallel tail: scores -> softmax -> ctx -> hid -> logits
    scores_kernel <<<dim3(8, 4, B_), 256, 0, stream>>>(h2all, k216, kb, raw);
    softmax_kernel<<<(size_t)B_*T_, 512, 0, stream>>>(raw, out_attn, attnb, attnlo);
    ctx_kernel    <<<dim3(8, 4, B_), 256, 0, stream>>>(attnb, attnlo, vT16, ctxb);
    hid_kernel    <<<dim3(4, 256), 512, 0, stream>>>(h2all, ctxb, W116, b1, hid);
    logits_kernel <<<dim3(8, 256), 512, 0, stream>>>(hid, emb16, bcls, out_logits);
}